// Round 1
// baseline (30073.886 us; speedup 1.0000x reference)
//
#include <hip/hip_runtime.h>
#include <hip/hip_bf16.h>
#include <math.h>

#define B_ 16
#define T_ 256
#define D_ 1024
#define H_ 1024
#define S_ 16
#define SCALE_ (1.0f/32.0f)   // 1/sqrt(1024)

__device__ __forceinline__ float sigm(float x) { return 1.f / (1.f + expf(-x)); }

__device__ __forceinline__ float block_sum256(float v) {
  __shared__ float lds[4];
  #pragma unroll
  for (int off = 32; off; off >>= 1) v += __shfl_down(v, off);
  int w = threadIdx.x >> 6;
  if ((threadIdx.x & 63) == 0) lds[w] = v;
  __syncthreads();
  float r = lds[0] + lds[1] + lds[2] + lds[3];
  __syncthreads();
  return r;
}

// C[M,N] = act( ascale * A[M,K] @ W[N,K]^T + bias )
// A row-major (lda=K), W row-major (ldw=K). M,N multiples of 64, K multiple of 16.
template<int ACT>  // 0=none 1=relu 2=sigmoid
__global__ __launch_bounds__(256)
void gemm_tn(const float* __restrict__ A, const float* __restrict__ W,
             const float* __restrict__ bias, float* __restrict__ C,
             int M, int N, int K, float ascale)
{
  __shared__ float As[16][64];
  __shared__ float Ws[16][64];
  const int tid = threadIdx.x;
  const int tx = tid & 15, ty = tid >> 4;
  const int m0 = blockIdx.y * 64, n0 = blockIdx.x * 64;
  const int lr = tid >> 2;         // 0..63
  const int lk = (tid & 3) * 4;    // 0,4,8,12
  float acc[4][4] = {};
  for (int k0 = 0; k0 < K; k0 += 16) {
    float4 av = *(const float4*)(A + (size_t)(m0 + lr) * K + k0 + lk);
    float4 wv = *(const float4*)(W + (size_t)(n0 + lr) * K + k0 + lk);
    __syncthreads();
    As[lk+0][lr] = av.x; As[lk+1][lr] = av.y; As[lk+2][lr] = av.z; As[lk+3][lr] = av.w;
    Ws[lk+0][lr] = wv.x; Ws[lk+1][lr] = wv.y; Ws[lk+2][lr] = wv.z; Ws[lk+3][lr] = wv.w;
    __syncthreads();
    #pragma unroll
    for (int k = 0; k < 16; ++k) {
      float a[4], b[4];
      #pragma unroll
      for (int i = 0; i < 4; ++i) a[i] = As[k][ty*4+i];
      #pragma unroll
      for (int j = 0; j < 4; ++j) b[j] = Ws[k][tx*4+j];
      #pragma unroll
      for (int i = 0; i < 4; ++i)
        #pragma unroll
        for (int j = 0; j < 4; ++j) acc[i][j] += a[i] * b[j];
    }
  }
  #pragma unroll
  for (int i = 0; i < 4; ++i) {
    int m = m0 + ty*4 + i;
    #pragma unroll
    for (int j = 0; j < 4; ++j) {
      int n = n0 + tx*4 + j;
      float v = acc[i][j] * ascale + (bias ? bias[n] : 0.f);
      if (ACT == 1) v = fmaxf(v, 0.f);
      else if (ACT == 2) v = sigm(v);
      C[(size_t)m * N + n] = v;
    }
  }
}

// LayerNorm(+relu) in place over rows of 1024
__global__ __launch_bounds__(256)
void ln_relu_inplace(float* __restrict__ X, const float* __restrict__ g,
                     const float* __restrict__ be)
{
  size_t row = blockIdx.x;
  float* p = X + row * 1024;
  int tid = threadIdx.x;
  float4 v = ((const float4*)p)[tid];
  float s = block_sum256(v.x + v.y + v.z + v.w);
  float mean = s * (1.f / 1024.f);
  float dx = v.x - mean, dy = v.y - mean, dz = v.z - mean, dw = v.w - mean;
  float ss = block_sum256(dx*dx + dy*dy + dz*dz + dw*dw);
  float r = rsqrtf(ss * (1.f / 1024.f) + 1e-5f);
  int c4 = tid * 4;
  float4 o;
  o.x = fmaxf(dx * r * g[c4+0] + be[c4+0], 0.f);
  o.y = fmaxf(dy * r * g[c4+1] + be[c4+1], 0.f);
  o.z = fmaxf(dz * r * g[c4+2] + be[c4+2], 0.f);
  o.w = fmaxf(dw * r * g[c4+3] + be[c4+3], 0.f);
  ((float4*)p)[tid] = o;
}

// final LN+relu, rows are (t*B+b), output [b][t][h]
__global__ __launch_bounds__(256)
void ln_relu_final(const float* __restrict__ F, const float* __restrict__ g,
                   const float* __restrict__ be, float* __restrict__ out)
{
  int row = blockIdx.x;           // t*16 + b
  int t = row >> 4, b = row & 15;
  const float4* p = (const float4*)(F + (size_t)row * 1024);
  int tid = threadIdx.x;
  float4 v = p[tid];
  float s = block_sum256(v.x + v.y + v.z + v.w);
  float mean = s * (1.f / 1024.f);
  float dx = v.x - mean, dy = v.y - mean, dz = v.z - mean, dw = v.w - mean;
  float ss = block_sum256(dx*dx + dy*dy + dz*dz + dw*dw);
  float r = rsqrtf(ss * (1.f / 1024.f) + 1e-5f);
  int c4 = tid * 4;
  float4 o;
  o.x = fmaxf(dx * r * g[c4+0] + be[c4+0], 0.f);
  o.y = fmaxf(dy * r * g[c4+1] + be[c4+1], 0.f);
  o.z = fmaxf(dz * r * g[c4+2] + be[c4+2], 0.f);
  o.w = fmaxf(dw * r * g[c4+3] + be[c4+3], 0.f);
  ((float4*)(out + ((size_t)b * T_ + t) * 1024))[tid] = o;
}

// layer-0 LSTM step: block owns 16 columns j0..j0+15 across all 4 gates, all 16 batches
__global__ __launch_bounds__(256)
void lstm0_step(const float* __restrict__ Z0,   // [B,T,4H] includes b_ih0
                const float* __restrict__ Whh,  // [4H,H]
                const float* __restrict__ bhh,  // [4H]
                const float* __restrict__ h_in,
                float* __restrict__ h_out,
                float* __restrict__ c,
                int t)
{
  __shared__ float Hs[16][16];
  __shared__ float Ws[16][64];
  __shared__ float zs[16][64];
  const int tid = threadIdx.x;
  const int tx = tid & 15, ty = tid >> 4;
  const int j0 = blockIdx.x * 16;
  const int lr = tid >> 2;
  const int lk = (tid & 3) * 4;
  const int wrow = (lr >> 4) * 1024 + j0 + (lr & 15);
  const int hm = tid >> 4, hk = tid & 15;
  float acc[4] = {0.f, 0.f, 0.f, 0.f};
  for (int k0 = 0; k0 < 1024; k0 += 16) {
    float4 wv = *(const float4*)(Whh + (size_t)wrow * 1024 + k0 + lk);
    float hv = h_in[hm * 1024 + k0 + hk];
    __syncthreads();
    Ws[lk+0][lr] = wv.x; Ws[lk+1][lr] = wv.y; Ws[lk+2][lr] = wv.z; Ws[lk+3][lr] = wv.w;
    Hs[hk][hm] = hv;
    __syncthreads();
    #pragma unroll
    for (int k = 0; k < 16; ++k) {
      float a = Hs[k][ty];
      #pragma unroll
      for (int j = 0; j < 4; ++j) acc[j] += a * Ws[k][tx*4 + j];
    }
  }
  __syncthreads();
  #pragma unroll
  for (int j = 0; j < 4; ++j) zs[ty][tx*4 + j] = acc[j];
  __syncthreads();
  const int b_ = tid >> 4, jj = tid & 15, j = j0 + jj;
  const size_t zoff = ((size_t)b_ * T_ + t) * 4096;
  float zi = zs[b_][jj]      + Z0[zoff + j]          + bhh[j];
  float zf = zs[b_][16 + jj] + Z0[zoff + 1024 + j]   + bhh[1024 + j];
  float zg = zs[b_][32 + jj] + Z0[zoff + 2048 + j]   + bhh[2048 + j];
  float zo = zs[b_][48 + jj] + Z0[zoff + 3072 + j]   + bhh[3072 + j];
  float cp = sigm(zf) * c[b_ * 1024 + j] + sigm(zi) * tanhf(zg);
  c[b_ * 1024 + j] = cp;
  h_out[b_ * 1024 + j] = sigm(zo) * tanhf(cp);
}

// layer-1 LSTM step: K=2048 over [h0_new ; h1_cur] with [W_ih1 ; W_hh1]
__global__ __launch_bounds__(256)
void lstm1_step(const float* __restrict__ h0new,
                const float* __restrict__ Wih,
                const float* __restrict__ Whh,
                const float* __restrict__ bih,
                const float* __restrict__ bhh,
                const float* __restrict__ h_in,
                float* __restrict__ h_out,
                float* __restrict__ c,
                float* __restrict__ h1_all,   // [T*B, H]
                float* __restrict__ ksum,     // [S*B, H]
                int t)
{
  __shared__ float Hs[16][16];
  __shared__ float Ws[16][64];
  __shared__ float zs[16][64];
  const int tid = threadIdx.x;
  const int tx = tid & 15, ty = tid >> 4;
  const int j0 = blockIdx.x * 16;
  const int lr = tid >> 2;
  const int lk = (tid & 3) * 4;
  const int wrow = (lr >> 4) * 1024 + j0 + (lr & 15);
  const int hm = tid >> 4, hk = tid & 15;
  float acc[4] = {0.f, 0.f, 0.f, 0.f};
  #pragma unroll
  for (int half = 0; half < 2; ++half) {
    const float* src = half ? h_in : h0new;
    const float* Wm  = half ? Whh : Wih;
    for (int k0 = 0; k0 < 1024; k0 += 16) {
      float4 wv = *(const float4*)(Wm + (size_t)wrow * 1024 + k0 + lk);
      float hv = src[hm * 1024 + k0 + hk];
      __syncthreads();
      Ws[lk+0][lr] = wv.x; Ws[lk+1][lr] = wv.y; Ws[lk+2][lr] = wv.z; Ws[lk+3][lr] = wv.w;
      Hs[hk][hm] = hv;
      __syncthreads();
      #pragma unroll
      for (int k = 0; k < 16; ++k) {
        float a = Hs[k][ty];
        #pragma unroll
        for (int j = 0; j < 4; ++j) acc[j] += a * Ws[k][tx*4 + j];
      }
    }
  }
  __syncthreads();
  #pragma unroll
  for (int j = 0; j < 4; ++j) zs[ty][tx*4 + j] = acc[j];
  __syncthreads();
  const int b_ = tid >> 4, jj = tid & 15, j = j0 + jj;
  float zi = zs[b_][jj]      + bih[j]        + bhh[j];
  float zf = zs[b_][16 + jj] + bih[1024 + j] + bhh[1024 + j];
  float zg = zs[b_][32 + jj] + bih[2048 + j] + bhh[2048 + j];
  float zo = zs[b_][48 + jj] + bih[3072 + j] + bhh[3072 + j];
  float cp = sigm(zf) * c[b_ * 1024 + j] + sigm(zi) * tanhf(zg);
  c[b_ * 1024 + j] = cp;
  float hv1 = sigm(zo) * tanhf(cp);
  h_out[b_ * 1024 + j] = hv1;
  h1_all[((size_t)t * 16 + b_) * 1024 + j] = hv1;
  ksum[((size_t)(t >> 4) * 16 + b_) * 1024 + j] += hv1;
}

// gather segment-final h1 rows into VIN [S*B, H]
__global__ __launch_bounds__(256)
void vgather(const float* __restrict__ H1A, float* __restrict__ VIN)
{
  int i = blockIdx.x * 256 + threadIdx.x;   // float4 index over 256*256
  if (i >= S_ * B_ * H_ / 4) return;
  int row = i >> 8, col = i & 255;
  int s = row >> 4, b = row & 15;
  int src = (s * 16 + 15) * 16 + b;
  ((float4*)VIN)[(size_t)row * 256 + col] = ((const float4*)H1A)[(size_t)src * 256 + col];
}

// per-(b,t) masked softmax attention over cached segments
__global__ __launch_bounds__(256)
void attn_kernel(const float* __restrict__ Q,      // [T*B, H]
                 const float* __restrict__ kbank,  // [S*B, H]
                 const float* __restrict__ vbank,  // [S*B, H]
                 float* __restrict__ R)            // [T*B, H]
{
  int row = blockIdx.x;          // t*16 + b
  int t = row >> 4, b = row & 15;
  int si = t >> 4;               // number of valid cached segments
  int tid = threadIdx.x, lane = tid & 63, w = tid >> 6;
  if (si == 0) {
    float4 z = {0.f, 0.f, 0.f, 0.f};
    ((float4*)(R + (size_t)row * 1024))[tid] = z;
    return;
  }
  __shared__ float sc[16];
  const float* q = Q + (size_t)row * 1024;
  for (int s = w; s < si; s += 4) {
    const float* kk = kbank + ((size_t)s * 16 + b) * 1024;
    float p = 0.f;
    for (int k = lane; k < 1024; k += 64) p += q[k] * kk[k];
    #pragma unroll
    for (int off = 32; off; off >>= 1) p += __shfl_down(p, off);
    if (lane == 0) sc[s] = p * SCALE_;
  }
  __syncthreads();
  float mx = -1e30f;
  for (int s = 0; s < si; ++s) mx = fmaxf(mx, sc[s]);
  float den = 0.f;
  for (int s = 0; s < si; ++s) den += expf(sc[s] - mx);
  float inv = 1.f / den;
  float4 accv = {0.f, 0.f, 0.f, 0.f};
  for (int s = 0; s < si; ++s) {
    float a = expf(sc[s] - mx) * inv;
    float4 vv = ((const float4*)(vbank + ((size_t)s * 16 + b) * 1024))[tid];
    accv.x += a * vv.x; accv.y += a * vv.y; accv.z += a * vv.z; accv.w += a * vv.w;
  }
  ((float4*)(R + (size_t)row * 1024))[tid] = accv;
}

// GI = [h1, R, h1-R]  (rows t*B+b, K=3072)
__global__ __launch_bounds__(256)
void build_gi(const float* __restrict__ H1, const float* __restrict__ R,
              float* __restrict__ GI)
{
  int i = blockIdx.x * 256 + threadIdx.x;  // float4 over 4096*768
  if (i >= 4096 * 768) return;
  int r = i / 768, kq = i % 768;
  const float4* h = (const float4*)(H1 + (size_t)r * 1024);
  const float4* rr = (const float4*)(R + (size_t)r * 1024);
  float4 v;
  if (kq < 256) v = h[kq];
  else if (kq < 512) v = rr[kq - 256];
  else {
    float4 a = h[kq - 512], b2 = rr[kq - 512];
    v.x = a.x - b2.x; v.y = a.y - b2.y; v.z = a.z - b2.z; v.w = a.w - b2.w;
  }
  ((float4*)GI)[(size_t)r * 768 + kq] = v;
}

// mix = gate*h1 + (1-gate)*R
__global__ __launch_bounds__(256)
void build_mix(const float* __restrict__ G, const float* __restrict__ H1,
               const float* __restrict__ R, float* __restrict__ M)
{
  int i = blockIdx.x * 256 + threadIdx.x;  // float4 over 4096*256
  if (i >= 4096 * 256) return;
  float4 g = ((const float4*)G)[i];
  float4 h = ((const float4*)H1)[i];
  float4 r = ((const float4*)R)[i];
  float4 m;
  m.x = g.x * h.x + (1.f - g.x) * r.x;
  m.y = g.y * h.y + (1.f - g.y) * r.y;
  m.z = g.z * h.z + (1.f - g.z) * r.z;
  m.w = g.w * h.w + (1.f - g.w) * r.w;
  ((float4*)M)[i] = m;
}

// CAT = [h1, (si>0 ? out : 0)]  (K=2048)
__global__ __launch_bounds__(256)
void build_cat(const float* __restrict__ H1, const float* __restrict__ O,
               float* __restrict__ C)
{
  int i = blockIdx.x * 256 + threadIdx.x;  // float4 over 4096*512
  if (i >= 4096 * 512) return;
  int r = i >> 9, kq = i & 511;
  float4 v;
  if (kq < 256) v = ((const float4*)H1)[(size_t)r * 256 + kq];
  else if (r >= 256) v = ((const float4*)O)[(size_t)r * 256 + (kq - 256)];
  else { v.x = v.y = v.z = v.w = 0.f; }
  ((float4*)C)[(size_t)r * 512 + kq] = v;
}

extern "C" void kernel_launch(void* const* d_in, const int* in_sizes, int n_in,
                              void* d_out, int out_size, void* d_ws, size_t ws_size,
                              hipStream_t stream) {
  const float* x     = (const float*)d_in[0];
  const float* W_ip  = (const float*)d_in[1];
  const float* b_ip  = (const float*)d_in[2];
  const float* g_ip  = (const float*)d_in[3];
  const float* be_ip = (const float*)d_in[4];
  const float* W_ih0 = (const float*)d_in[5];
  const float* W_hh0 = (const float*)d_in[6];
  const float* b_ih0 = (const float*)d_in[7];
  const float* b_hh0 = (const float*)d_in[8];
  const float* W_ih1 = (const float*)d_in[9];
  const float* W_hh1 = (const float*)d_in[10];
  const float* b_ih1 = (const float*)d_in[11];
  const float* b_hh1 = (const float*)d_in[12];
  const float* Wq    = (const float*)d_in[13];
  const float* Wk    = (const float*)d_in[14];
  const float* Wv    = (const float*)d_in[15];
  const float* Wg1   = (const float*)d_in[16];
  const float* bg1   = (const float*)d_in[17];
  const float* Wg2   = (const float*)d_in[18];
  const float* bg2   = (const float*)d_in[19];
  const float* Wo    = (const float*)d_in[20];
  const float* bo    = (const float*)d_in[21];
  const float* Wf    = (const float*)d_in[22];
  const float* bff   = (const float*)d_in[23];
  const float* g_f   = (const float*)d_in[24];
  const float* be_f  = (const float*)d_in[25];
  float* out = (float*)d_out;
  char* ws = (char*)d_ws;
  const size_t MB = (size_t)1 << 20;

  float* XP   = (float*)(ws + 0);        // 16MB  (later: gate)
  float* Z0   = (float*)(ws + 16 * MB);  // 64MB  (later: GI 48MB, then CAT 32MB)
  float* GI   = Z0;
  float* CAT  = Z0;
  float* G1   = (float*)(ws + 80 * MB);  // 16MB  (later: out)
  float* OUTB = G1;
  float* H1A  = (float*)(ws + 96 * MB);  // 16MB
  float* Q    = (float*)(ws + 112 * MB); // 16MB  (later: mix, then F)
  float* MIX  = Q;
  float* FB   = Q;
  float* R    = (float*)(ws + 128 * MB); // 16MB
  float* VIN  = (float*)(ws + 144 * MB); // 1MB
  float* ST   = (float*)(ws + 145 * MB);
  float* h0a  = ST;
  float* h0b  = ST + 16 * 1024;
  float* c0   = ST + 2 * 16 * 1024;
  float* h1a  = ST + 3 * 16 * 1024;
  float* h1b  = ST + 4 * 16 * 1024;
  float* c1   = ST + 5 * 16 * 1024;
  float* KSUM = ST + 6 * 16 * 1024;           // 256*1024
  float* KB   = KSUM + 256 * 1024;            // kbank
  float* VB   = KB + 256 * 1024;              // vbank

  // zero recurrent state + ksum (replayed every call)
  hipMemsetAsync(ST, 0, (6 * 16 * 1024 + 256 * 1024) * sizeof(float), stream);

  dim3 blk(256);
  // Phase A: xp = relu(LN(x@W_ip^T + b_ip))
  gemm_tn<0><<<dim3(D_/64, (B_*T_)/64), blk, 0, stream>>>(x, W_ip, b_ip, XP, B_*T_, D_, D_, 1.f);
  ln_relu_inplace<<<B_*T_, blk, 0, stream>>>(XP, g_ip, be_ip);
  // Phase B: Z0 = xp@W_ih0^T + b_ih0
  gemm_tn<0><<<dim3(4*H_/64, (B_*T_)/64), blk, 0, stream>>>(XP, W_ih0, b_ih0, Z0, B_*T_, 4*H_, D_, 1.f);
  // Phase C: sequential 256 steps (double-buffered h states)
  for (int t = 0; t < T_; ++t) {
    const float* h0in = (t & 1) ? h0b : h0a;
    float* h0out      = (t & 1) ? h0a : h0b;
    const float* h1in = (t & 1) ? h1b : h1a;
    float* h1out      = (t & 1) ? h1a : h1b;
    lstm0_step<<<64, blk, 0, stream>>>(Z0, W_hh0, b_hh0, h0in, h0out, c0, t);
    lstm1_step<<<64, blk, 0, stream>>>(h0out, W_ih1, W_hh1, b_ih1, b_hh1,
                                       h1in, h1out, c1, H1A, KSUM, t);
  }
  // Phase D: kbank = (ksum/16)@Wk^T ; vbank = h1_seg_last@Wv^T
  gemm_tn<0><<<dim3(H_/64, (S_*B_)/64), blk, 0, stream>>>(KSUM, Wk, nullptr, KB, S_*B_, H_, H_, 1.f/16.f);
  vgather<<<dim3((S_*B_*H_/4 + 255)/256), blk, 0, stream>>>(H1A, VIN);
  gemm_tn<0><<<dim3(H_/64, (S_*B_)/64), blk, 0, stream>>>(VIN, Wv, nullptr, VB, S_*B_, H_, H_, 1.f);
  // Phase E: batched retrieval + gate + output path
  gemm_tn<0><<<dim3(H_/64, (B_*T_)/64), blk, 0, stream>>>(H1A, Wq, nullptr, Q, B_*T_, H_, H_, 1.f);
  attn_kernel<<<B_*T_, blk, 0, stream>>>(Q, KB, VB, R);
  build_gi<<<(4096*768 + 255)/256, blk, 0, stream>>>(H1A, R, GI);
  gemm_tn<1><<<dim3(H_/64, (B_*T_)/64), blk, 0, stream>>>(GI, Wg1, bg1, G1, B_*T_, H_, 3*H_, 1.f);
  gemm_tn<2><<<dim3(H_/64, (B_*T_)/64), blk, 0, stream>>>(G1, Wg2, bg2, XP, B_*T_, H_, H_, 1.f);
  build_mix<<<(4096*256 + 255)/256, blk, 0, stream>>>(XP, H1A, R, MIX);
  gemm_tn<0><<<dim3(H_/64, (B_*T_)/64), blk, 0, stream>>>(MIX, Wo, bo, OUTB, B_*T_, H_, H_, 1.f);
  build_cat<<<(4096*512 + 255)/256, blk, 0, stream>>>(H1A, OUTB, CAT);
  gemm_tn<0><<<dim3(H_/64, (B_*T_)/64), blk, 0, stream>>>(CAT, Wf, bff, FB, B_*T_, H_, 2*H_, 1.f);
  ln_relu_final<<<B_*T_, blk, 0, stream>>>(FB, g_f, be_f, out);
}

// Round 2
// 5301.746 us; speedup vs baseline: 5.6724x; 5.6724x over previous
//
#include <hip/hip_runtime.h>
#include <hip/hip_bf16.h>
#include <math.h>

#define B_ 16
#define T_ 256
#define D_ 1024
#define H_ 1024
#define S_ 16
#define SCALE_ (1.0f/32.0f)   // 1/sqrt(1024)

typedef __attribute__((ext_vector_type(8))) short short8v;
typedef __attribute__((ext_vector_type(4))) float f32x4;

__device__ __forceinline__ float sigm(float x) { return 1.f / (1.f + expf(-x)); }

__device__ __forceinline__ ushort f2b(float v) {
  __hip_bfloat16 h = __float2bfloat16(v);
  return *reinterpret_cast<ushort*>(&h);
}
__device__ __forceinline__ float b2f(ushort u) {
  union { unsigned u32; float f; } x; x.u32 = ((unsigned)u) << 16; return x.f;
}

__device__ __forceinline__ void glds16(const void* g, void* l) {
  __builtin_amdgcn_global_load_lds((const __attribute__((address_space(1))) void*)g,
                                   (__attribute__((address_space(3))) void*)l, 16, 0, 0);
}

__device__ __forceinline__ float block_sum256(float v) {
  __shared__ float lds[4];
  #pragma unroll
  for (int off = 32; off; off >>= 1) v += __shfl_down(v, off);
  int w = threadIdx.x >> 6;
  if ((threadIdx.x & 63) == 0) lds[w] = v;
  __syncthreads();
  float r = lds[0] + lds[1] + lds[2] + lds[3];
  __syncthreads();
  return r;
}

// ---------------- fp32 -> bf16 convert ----------------
__global__ __launch_bounds__(256)
void cvt_bf16(const float* __restrict__ in, ushort* __restrict__ out, int n)
{
  int i = (blockIdx.x * 256 + threadIdx.x) * 4;
  if (i >= n) return;
  float4 v = *(const float4*)(in + i);
  ushort4 o; o.x = f2b(v.x); o.y = f2b(v.y); o.z = f2b(v.z); o.w = f2b(v.w);
  *(ushort4*)(out + i) = o;
}

// ---------------- MFMA bf16 GEMM: C = act(ascale * A@W^T + bias) ----------------
// A[M,K] bf16 row-major, W[N,K] bf16 row-major. M%128==0, N%128==0, K%64==0.
// REMAP: output row m=b*256+t stored at row t*16+b (M must be 4096).
template<int ACT, int REMAP>   // ACT: 0 none, 1 relu, 2 sigmoid
__global__ __launch_bounds__(256)
void gemm_bf16(const ushort* __restrict__ A, const ushort* __restrict__ W,
               const float* __restrict__ bias,
               float* __restrict__ Cf, ushort* __restrict__ Cb,
               int M, int N, int K, float ascale)
{
  __shared__ char As[16384];
  __shared__ char Bs[16384];
  const int tid = threadIdx.x;
  const int w = tid >> 6, l = tid & 63;
  const int m0 = blockIdx.y * 128, n0 = blockIdx.x * 128;
  const int wm = w >> 1, wn = w & 1;
  const int srow = l >> 3;                        // row within 8-row chunk
  const int sbyte = ((l & 7) * 16) ^ (srow << 4); // pre-swizzled source column byte
  f32x4 acc[4][4];
  #pragma unroll
  for (int i = 0; i < 4; ++i)
    #pragma unroll
    for (int j = 0; j < 4; ++j) acc[i][j] = (f32x4){0.f, 0.f, 0.f, 0.f};

  for (int k0 = 0; k0 < K; k0 += 64) {
    __syncthreads();
    #pragma unroll
    for (int c = 0; c < 4; ++c) {
      int ca = w * 4 + c;            // chunk 0..15 (8 rows each)
      int r = ca * 8 + srow;
      glds16((const char*)A + (((size_t)(m0 + r) * K + k0) << 1) + sbyte, As + ca * 1024);
      glds16((const char*)W + (((size_t)(n0 + r) * K + k0) << 1) + sbyte, Bs + ca * 1024);
    }
    __syncthreads();
    #pragma unroll
    for (int ks = 0; ks < 2; ++ks) {
      short8v a[4], b[4];
      int qb = ks * 64 + (l >> 4) * 16;
      #pragma unroll
      for (int i = 0; i < 4; ++i) {
        int ra = wm * 64 + i * 16 + (l & 15);
        a[i] = *(const short8v*)(As + ra * 128 + (qb ^ ((ra & 7) << 4)));
        int rb = wn * 64 + i * 16 + (l & 15);
        b[i] = *(const short8v*)(Bs + rb * 128 + (qb ^ ((rb & 7) << 4)));
      }
      #pragma unroll
      for (int i = 0; i < 4; ++i)
        #pragma unroll
        for (int j = 0; j < 4; ++j)
          acc[i][j] = __builtin_amdgcn_mfma_f32_16x16x32_bf16(a[i], b[j], acc[i][j], 0, 0, 0);
    }
  }
  #pragma unroll
  for (int i = 0; i < 4; ++i) {
    #pragma unroll
    for (int j = 0; j < 4; ++j) {
      int n = n0 + wn * 64 + j * 16 + (l & 15);
      float bv = bias ? bias[n] : 0.f;
      #pragma unroll
      for (int q = 0; q < 4; ++q) {
        int m = m0 + wm * 64 + i * 16 + (l >> 4) * 4 + q;
        float v = acc[i][j][q] * ascale + bv;
        if (ACT == 1) v = fmaxf(v, 0.f);
        if (ACT == 2) v = sigm(v);
        size_t off = REMAP ? ((size_t)((m & 255) * 16 + (m >> 8)) * N + n)
                           : ((size_t)m * N + n);
        if (Cf) Cf[off] = v;
        if (Cb) Cb[off] = f2b(v);
      }
    }
  }
}

// ---------------- LayerNorm+relu: f32 in -> bf16 out ----------------
__global__ __launch_bounds__(256)
void ln_relu_bf16(const float* __restrict__ X, const float* __restrict__ g,
                  const float* __restrict__ be, ushort* __restrict__ out)
{
  size_t row = blockIdx.x;
  const float4* p = (const float4*)(X + row * 1024);
  int tid = threadIdx.x;
  float4 v = p[tid];
  float s = block_sum256(v.x + v.y + v.z + v.w);
  float mean = s * (1.f / 1024.f);
  float dx = v.x - mean, dy = v.y - mean, dz = v.z - mean, dw = v.w - mean;
  float ss = block_sum256(dx*dx + dy*dy + dz*dz + dw*dw);
  float r = rsqrtf(ss * (1.f / 1024.f) + 1e-5f);
  int c4 = tid * 4;
  ushort4 o;
  o.x = f2b(fmaxf(dx * r * g[c4+0] + be[c4+0], 0.f));
  o.y = f2b(fmaxf(dy * r * g[c4+1] + be[c4+1], 0.f));
  o.z = f2b(fmaxf(dz * r * g[c4+2] + be[c4+2], 0.f));
  o.w = f2b(fmaxf(dw * r * g[c4+3] + be[c4+3], 0.f));
  *(ushort4*)(out + row * 1024 + c4) = o;
}

// final LN+relu: rows (t*B+b) f32 -> out [b][t][h] f32
__global__ __launch_bounds__(256)
void ln_relu_final(const float* __restrict__ F, const float* __restrict__ g,
                   const float* __restrict__ be, float* __restrict__ out)
{
  int row = blockIdx.x;           // t*16 + b
  int t = row >> 4, b = row & 15;
  const float4* p = (const float4*)(F + (size_t)row * 1024);
  int tid = threadIdx.x;
  float4 v = p[tid];
  float s = block_sum256(v.x + v.y + v.z + v.w);
  float mean = s * (1.f / 1024.f);
  float dx = v.x - mean, dy = v.y - mean, dz = v.z - mean, dw = v.w - mean;
  float ss = block_sum256(dx*dx + dy*dy + dz*dz + dw*dw);
  float r = rsqrtf(ss * (1.f / 1024.f) + 1e-5f);
  int c4 = tid * 4;
  float4 o;
  o.x = fmaxf(dx * r * g[c4+0] + be[c4+0], 0.f);
  o.y = fmaxf(dy * r * g[c4+1] + be[c4+1], 0.f);
  o.z = fmaxf(dz * r * g[c4+2] + be[c4+2], 0.f);
  o.w = fmaxf(dw * r * g[c4+3] + be[c4+3], 0.f);
  ((float4*)(out + ((size_t)b * T_ + t) * 1024))[tid] = o;
}

// ---------------- LSTM layer-0 step (MFMA matvec, M=16=batch) ----------------
// 64 blocks x 512 threads. Wave w: gate g=w&3, K-half kh=w>>2, 16 output cols.
__global__ __launch_bounds__(512)
void lstm0_mfma(const ushort* __restrict__ Z0T,  // [T*B,4096] bf16 (incl b_ih0)
                const ushort* __restrict__ Whh,  // [4096,1024] bf16
                const float* __restrict__ bhh,
                const ushort* __restrict__ hin, ushort* __restrict__ hout,
                float* __restrict__ c0, int t)
{
  __shared__ char Ah[32768];          // h staged: off(kc,m)=kc*256+((m^(kc&15))<<4)
  __shared__ float zs[8][16][16];     // [kh*4+g][batch][col]
  const int tid = threadIdx.x, w = tid >> 6, l = tid & 63;
  #pragma unroll
  for (int it = 0; it < 4; ++it) {
    int g1k = w * 4 + it;             // 1KB chunk 0..31
    int kc = g1k * 4 + (l >> 4);      // 0..127
    int m = (l & 15) ^ (kc & 15);
    glds16((const char*)hin + (((size_t)m * 1024 + kc * 8) << 1), Ah + g1k * 1024);
  }
  __syncthreads();
  const int g = w & 3, kh = w >> 2;
  const int j0 = blockIdx.x * 16;
  const int n = g * 1024 + j0 + (l & 15);
  const ushort* wrow = Whh + (size_t)n * 1024 + kh * 512;
  f32x4 acc = (f32x4){0.f, 0.f, 0.f, 0.f};
  #pragma unroll
  for (int ks = 0; ks < 16; ++ks) {
    short8v bfrag = *(const short8v*)(wrow + ks * 32 + (l >> 4) * 8);
    int kc = kh * 64 + ks * 4 + (l >> 4);
    short8v afrag = *(const short8v*)(Ah + kc * 256 + (((l & 15) ^ (kc & 15)) << 4));
    acc = __builtin_amdgcn_mfma_f32_16x16x32_bf16(afrag, bfrag, acc, 0, 0, 0);
  }
  #pragma unroll
  for (int q = 0; q < 4; ++q)
    zs[kh * 4 + g][(l >> 4) * 4 + q][l & 15] = acc[q];
  __syncthreads();
  if (tid < 256) {
    int b = tid >> 4, jj = tid & 15, jf = j0 + jj;
    const size_t zrow = ((size_t)t * 16 + b) * 4096;
    float zi = zs[0][b][jj] + zs[4][b][jj] + b2f(Z0T[zrow + jf])        + bhh[jf];
    float zf = zs[1][b][jj] + zs[5][b][jj] + b2f(Z0T[zrow + 1024 + jf]) + bhh[1024 + jf];
    float zg = zs[2][b][jj] + zs[6][b][jj] + b2f(Z0T[zrow + 2048 + jf]) + bhh[2048 + jf];
    float zo = zs[3][b][jj] + zs[7][b][jj] + b2f(Z0T[zrow + 3072 + jf]) + bhh[3072 + jf];
    float cp = sigm(zf) * c0[b * 1024 + jf] + sigm(zi) * tanhf(zg);
    c0[b * 1024 + jf] = cp;
    hout[b * 1024 + jf] = f2b(sigm(zo) * tanhf(cp));
  }
}

// ---------------- LSTM layer-1 step (K=2048 over [h0new; h1]) ----------------
__global__ __launch_bounds__(512)
void lstm1_mfma(const ushort* __restrict__ Wih,  // [4096,1024] bf16
                const ushort* __restrict__ Whh,  // [4096,1024] bf16
                const float* __restrict__ bih, const float* __restrict__ bhh,
                const ushort* __restrict__ h0new, const ushort* __restrict__ h1in,
                ushort* __restrict__ h1out, float* __restrict__ c1,
                ushort* __restrict__ H1B,        // [T*B,1024] bf16
                float* __restrict__ KSUM,        // [S*B,1024] f32
                int t)
{
  __shared__ char Ah[65536];          // kc 0..127: h0new, 128..255: h1in
  __shared__ float zs[8][16][16];
  const int tid = threadIdx.x, w = tid >> 6, l = tid & 63;
  #pragma unroll
  for (int it = 0; it < 8; ++it) {
    int g1k = w * 8 + it;             // 0..63
    int kc = g1k * 4 + (l >> 4);      // 0..255
    int m = (l & 15) ^ (kc & 15);
    const char* src = (kc < 128)
      ? (const char*)h0new + (((size_t)m * 1024 + kc * 8) << 1)
      : (const char*)h1in  + (((size_t)m * 1024 + (kc - 128) * 8) << 1);
    glds16(src, Ah + g1k * 1024);
  }
  __syncthreads();
  const int g = w & 3, kh = w >> 2;
  const int j0 = blockIdx.x * 16;
  const int n = g * 1024 + j0 + (l & 15);
  const ushort* wrow = (kh ? Whh : Wih) + (size_t)n * 1024;
  f32x4 acc = (f32x4){0.f, 0.f, 0.f, 0.f};
  #pragma unroll
  for (int ks = 0; ks < 32; ++ks) {
    short8v bfrag = *(const short8v*)(wrow + ks * 32 + (l >> 4) * 8);
    int kc = kh * 128 + ks * 4 + (l >> 4);
    short8v afrag = *(const short8v*)(Ah + kc * 256 + (((l & 15) ^ (kc & 15)) << 4));
    acc = __builtin_amdgcn_mfma_f32_16x16x32_bf16(afrag, bfrag, acc, 0, 0, 0);
  }
  #pragma unroll
  for (int q = 0; q < 4; ++q)
    zs[kh * 4 + g][(l >> 4) * 4 + q][l & 15] = acc[q];
  __syncthreads();
  if (tid < 256) {
    int b = tid >> 4, jj = tid & 15, jf = j0 + jj;
    float zi = zs[0][b][jj] + zs[4][b][jj] + bih[jf]        + bhh[jf];
    float zf = zs[1][b][jj] + zs[5][b][jj] + bih[1024 + jf] + bhh[1024 + jf];
    float zg = zs[2][b][jj] + zs[6][b][jj] + bih[2048 + jf] + bhh[2048 + jf];
    float zo = zs[3][b][jj] + zs[7][b][jj] + bih[3072 + jf] + bhh[3072 + jf];
    float cp = sigm(zf) * c1[b * 1024 + jf] + sigm(zi) * tanhf(zg);
    c1[b * 1024 + jf] = cp;
    float hv = sigm(zo) * tanhf(cp);
    ushort hb = f2b(hv);
    h1out[b * 1024 + jf] = hb;
    H1B[((size_t)t * 16 + b) * 1024 + jf] = hb;
    KSUM[((size_t)(t >> 4) * 16 + b) * 1024 + jf] += hv;
  }
}

// gather segment-final h1 rows (bf16) into VINB [S*B, H]
__global__ __launch_bounds__(256)
void vgather(const ushort* __restrict__ H1B, ushort* __restrict__ VINB)
{
  int i = blockIdx.x * 256 + threadIdx.x;   // 65536 threads, 4 bf16 each
  int row = i >> 8, c4 = (i & 255) * 4;
  int src = (row >> 4) * 256 + 240 + (row & 15);
  *(ushort4*)(VINB + (size_t)row * 1024 + c4) =
      *(const ushort4*)(H1B + (size_t)src * 1024 + c4);
}

// per-(b,t) masked softmax attention over cached segments (all f32)
__global__ __launch_bounds__(256)
void attn_kernel(const float* __restrict__ Q, const float* __restrict__ kbank,
                 const float* __restrict__ vbank, float* __restrict__ R)
{
  int row = blockIdx.x;          // t*16 + b
  int t = row >> 4, b = row & 15;
  int si = t >> 4;
  int tid = threadIdx.x, lane = tid & 63, w = tid >> 6;
  if (si == 0) {
    float4 z = {0.f, 0.f, 0.f, 0.f};
    ((float4*)(R + (size_t)row * 1024))[tid] = z;
    return;
  }
  __shared__ float sc[16];
  const float* q = Q + (size_t)row * 1024;
  for (int s = w; s < si; s += 4) {
    const float* kk = kbank + ((size_t)s * 16 + b) * 1024;
    float p = 0.f;
    for (int k = lane; k < 1024; k += 64) p += q[k] * kk[k];
    #pragma unroll
    for (int off = 32; off; off >>= 1) p += __shfl_down(p, off);
    if (lane == 0) sc[s] = p * SCALE_;
  }
  __syncthreads();
  float mx = -1e30f;
  for (int s = 0; s < si; ++s) mx = fmaxf(mx, sc[s]);
  float den = 0.f;
  for (int s = 0; s < si; ++s) den += expf(sc[s] - mx);
  float inv = 1.f / den;
  float4 accv = {0.f, 0.f, 0.f, 0.f};
  for (int s = 0; s < si; ++s) {
    float a = expf(sc[s] - mx) * inv;
    float4 vv = ((const float4*)(vbank + ((size_t)s * 16 + b) * 1024))[tid];
    accv.x += a * vv.x; accv.y += a * vv.y; accv.z += a * vv.z; accv.w += a * vv.w;
  }
  ((float4*)(R + (size_t)row * 1024))[tid] = accv;
}

// GI = [h1, R, h1-R] bf16, K=3072
__global__ __launch_bounds__(256)
void build_gi(const ushort* __restrict__ H1B, const float* __restrict__ R,
              ushort* __restrict__ GI)
{
  size_t r = blockIdx.x;
  int c4 = threadIdx.x * 4;
  ushort4 h4 = *(const ushort4*)(H1B + r * 1024 + c4);
  float4 rv = *(const float4*)(R + r * 1024 + c4);
  *(ushort4*)(GI + r * 3072 + c4) = h4;
  ushort4 rb; rb.x = f2b(rv.x); rb.y = f2b(rv.y); rb.z = f2b(rv.z); rb.w = f2b(rv.w);
  *(ushort4*)(GI + r * 3072 + 1024 + c4) = rb;
  ushort4 d;
  d.x = f2b(b2f(h4.x) - rv.x); d.y = f2b(b2f(h4.y) - rv.y);
  d.z = f2b(b2f(h4.z) - rv.z); d.w = f2b(b2f(h4.w) - rv.w);
  *(ushort4*)(GI + r * 3072 + 2048 + c4) = d;
}

// mix = gate*h1 + (1-gate)*R  -> bf16
__global__ __launch_bounds__(256)
void build_mix(const float* __restrict__ G, const ushort* __restrict__ H1B,
               const float* __restrict__ R, ushort* __restrict__ M)
{
  size_t r = blockIdx.x;
  int c4 = threadIdx.x * 4;
  float4 g = *(const float4*)(G + r * 1024 + c4);
  ushort4 h = *(const ushort4*)(H1B + r * 1024 + c4);
  float4 rv = *(const float4*)(R + r * 1024 + c4);
  ushort4 o;
  o.x = f2b(g.x * b2f(h.x) + (1.f - g.x) * rv.x);
  o.y = f2b(g.y * b2f(h.y) + (1.f - g.y) * rv.y);
  o.z = f2b(g.z * b2f(h.z) + (1.f - g.z) * rv.z);
  o.w = f2b(g.w * b2f(h.w) + (1.f - g.w) * rv.w);
  *(ushort4*)(M + r * 1024 + c4) = o;
}

// CAT = [h1, (t>=16 ? out : 0)] bf16, K=2048
__global__ __launch_bounds__(256)
void build_cat(const ushort* __restrict__ H1B, const float* __restrict__ O,
               ushort* __restrict__ C)
{
  size_t r = blockIdx.x;
  int c4 = threadIdx.x * 4;
  *(ushort4*)(C + r * 2048 + c4) = *(const ushort4*)(H1B + r * 1024 + c4);
  ushort4 o;
  if (r >= 256) {
    float4 v = *(const float4*)(O + r * 1024 + c4);
    o.x = f2b(v.x); o.y = f2b(v.y); o.z = f2b(v.z); o.w = f2b(v.w);
  } else { o.x = o.y = o.z = o.w = 0; }
  *(ushort4*)(C + r * 2048 + 1024 + c4) = o;
}

extern "C" void kernel_launch(void* const* d_in, const int* in_sizes, int n_in,
                              void* d_out, int out_size, void* d_ws, size_t ws_size,
                              hipStream_t stream) {
  const float* x     = (const float*)d_in[0];
  const float* W_ip  = (const float*)d_in[1];
  const float* b_ip  = (const float*)d_in[2];
  const float* g_ip  = (const float*)d_in[3];
  const float* be_ip = (const float*)d_in[4];
  const float* W_ih0 = (const float*)d_in[5];
  const float* W_hh0 = (const float*)d_in[6];
  const float* b_ih0 = (const float*)d_in[7];
  const float* b_hh0 = (const float*)d_in[8];
  const float* W_ih1 = (const float*)d_in[9];
  const float* W_hh1 = (const float*)d_in[10];
  const float* b_ih1 = (const float*)d_in[11];
  const float* b_hh1 = (const float*)d_in[12];
  const float* Wq    = (const float*)d_in[13];
  const float* Wk    = (const float*)d_in[14];
  const float* Wv    = (const float*)d_in[15];
  const float* Wg1   = (const float*)d_in[16];
  const float* bg1   = (const float*)d_in[17];
  const float* Wg2   = (const float*)d_in[18];
  const float* bg2   = (const float*)d_in[19];
  const float* Wo    = (const float*)d_in[20];
  const float* bo    = (const float*)d_in[21];
  const float* Wf    = (const float*)d_in[22];
  const float* bff   = (const float*)d_in[23];
  const float* g_f   = (const float*)d_in[24];
  const float* be_f  = (const float*)d_in[25];
  float* out = (float*)d_out;
  char* ws = (char*)d_ws;
  const size_t MB = (size_t)1 << 20;
  const size_t KB = (size_t)1 << 10;

  // bf16 weight pool (offsets in elements)
  ushort* WB = (ushort*)(ws);
  ushort* wipB  = WB;            // 1M
  ushort* wih0B = WB + 1*1048576; // 4M
  ushort* whh0B = WB + 5*1048576;
  ushort* wih1B = WB + 9*1048576;
  ushort* whh1B = WB + 13*1048576;
  ushort* wqB   = WB + 17*1048576;
  ushort* wkB   = WB + 18*1048576;
  ushort* wvB   = WB + 19*1048576;
  ushort* wg1B  = WB + 20*1048576; // 3M
  ushort* wg2B  = WB + 23*1048576;
  ushort* woB   = WB + 24*1048576;
  ushort* wfB   = WB + 25*1048576; // 2M -> ends 27M elems = 54MB

  ushort* XB   = (ushort*)(ws + 54 * MB);   // 8MB: x bf16, later XPB
  float*  XP   = (float*)(ws + 62 * MB);    // 16MB: input_proj pre-LN, later Q
  float*  Qf   = XP;
  char*   SCR  = ws + 78 * MB;              // 48MB scratch region
  ushort* Z0T  = (ushort*)SCR;              // 32MB bf16 [T*B,4096]
  ushort* GIB  = (ushort*)SCR;              // 24MB (after loop)
  ushort* G1B  = (ushort*)(SCR + 24 * MB);  // 8MB
  float*  GT   = (float*)(SCR + 32 * MB);   // 16MB
  ushort* MIXB = (ushort*)SCR;              // 8MB
  float*  OUTB = (float*)(SCR + 8 * MB);    // 16MB
  ushort* CATB = (ushort*)(SCR + 24 * MB);  // 16MB
  float*  FB   = (float*)SCR;               // 16MB
  ushort* H1B  = (ushort*)(ws + 126 * MB);  // 8MB
  float*  R    = (float*)(ws + 134 * MB);   // 16MB
  char*   ST   = ws + 150 * MB;
  ushort* h0Ba = (ushort*)(ST);
  ushort* h0Bb = (ushort*)(ST + 32 * KB);
  ushort* h1Ba = (ushort*)(ST + 64 * KB);
  ushort* h1Bb = (ushort*)(ST + 96 * KB);
  float*  c0   = (float*)(ST + 128 * KB);
  float*  c1   = (float*)(ST + 192 * KB);
  float*  KSUM = (float*)(ST + 256 * KB);         // 1MB
  ushort* KSB  = (ushort*)(ST + 1280 * KB);       // 0.5MB
  float*  KBf  = (float*)(ST + 1792 * KB);        // 1MB
  float*  VBf  = (float*)(ST + 2816 * KB);        // 1MB
  ushort* VINB = (ushort*)(ST + 3840 * KB);       // 0.5MB

  // zero recurrent state + KSUM
  hipMemsetAsync(ST, 0, 1280 * KB, stream);

  dim3 blk(256);
  auto cvt = [&](const float* src, ushort* dst, int n) {
    cvt_bf16<<<dim3((n / 4 + 255) / 256), blk, 0, stream>>>(src, dst, n);
  };
  // weight + input conversions
  cvt(x,     XB,    4194304);
  cvt(W_ip,  wipB,  1048576);
  cvt(W_ih0, wih0B, 4194304);
  cvt(W_hh0, whh0B, 4194304);
  cvt(W_ih1, wih1B, 4194304);
  cvt(W_hh1, whh1B, 4194304);
  cvt(Wq,    wqB,   1048576);
  cvt(Wk,    wkB,   1048576);
  cvt(Wv,    wvB,   1048576);
  cvt(Wg1,   wg1B,  3145728);
  cvt(Wg2,   wg2B,  1048576);
  cvt(Wo,    woB,   1048576);
  cvt(Wf,    wfB,   2097152);

  // Phase A: XP = x@W_ip^T + b_ip ; XPB = relu(LN(XP)) (bf16, stored in XB space)
  gemm_bf16<0,0><<<dim3(1024/128, 4096/128), blk, 0, stream>>>(
      XB, wipB, b_ip, XP, nullptr, 4096, 1024, 1024, 1.f);
  ln_relu_bf16<<<4096, blk, 0, stream>>>(XP, g_ip, be_ip, XB);
  // Phase B: Z0T = XPB@W_ih0^T + b_ih0, rows remapped to t*16+b, bf16
  gemm_bf16<0,1><<<dim3(4096/128, 4096/128), blk, 0, stream>>>(
      XB, wih0B, b_ih0, nullptr, Z0T, 4096, 4096, 1024, 1.f);
  // Phase C: 256 sequential steps
  dim3 blk512(512);
  for (int t = 0; t < T_; ++t) {
    const ushort* h0in = (t & 1) ? h0Bb : h0Ba;
    ushort* h0out      = (t & 1) ? h0Ba : h0Bb;
    const ushort* h1in = (t & 1) ? h1Bb : h1Ba;
    ushort* h1out      = (t & 1) ? h1Ba : h1Bb;
    lstm0_mfma<<<64, blk512, 0, stream>>>(Z0T, whh0B, b_hh0, h0in, h0out, c0, t);
    lstm1_mfma<<<64, blk512, 0, stream>>>(wih1B, whh1B, b_ih1, b_hh1,
                                          h0out, h1in, h1out, c1, H1B, KSUM, t);
  }
  // Phase D: kbank / vbank
  cvt(KSUM, KSB, 262144);
  gemm_bf16<0,0><<<dim3(1024/128, 256/128), blk, 0, stream>>>(
      KSB, wkB, nullptr, KBf, nullptr, 256, 1024, 1024, 1.f/16.f);
  vgather<<<256, blk, 0, stream>>>(H1B, VINB);
  gemm_bf16<0,0><<<dim3(1024/128, 256/128), blk, 0, stream>>>(
      VINB, wvB, nullptr, VBf, nullptr, 256, 1024, 1024, 1.f);
  // Phase E: retrieval + gate + output
  gemm_bf16<0,0><<<dim3(1024/128, 4096/128), blk, 0, stream>>>(
      H1B, wqB, nullptr, Qf, nullptr, 4096, 1024, 1024, 1.f);
  attn_kernel<<<4096, blk, 0, stream>>>(Qf, KBf, VBf, R);
  build_gi<<<4096, blk, 0, stream>>>(H1B, R, GIB);
  gemm_bf16<1,0><<<dim3(1024/128, 4096/128), blk, 0, stream>>>(
      GIB, wg1B, bg1, nullptr, G1B, 4096, 1024, 3072, 1.f);
  gemm_bf16<2,0><<<dim3(1024/128, 4096/128), blk, 0, stream>>>(
      G1B, wg2B, bg2, GT, nullptr, 4096, 1024, 1024, 1.f);
  build_mix<<<4096, blk, 0, stream>>>(GT, H1B, R, MIXB);
  gemm_bf16<0,0><<<dim3(1024/128, 4096/128), blk, 0, stream>>>(
      MIXB, woB, bo, OUTB, nullptr, 4096, 1024, 1024, 1.f);
  build_cat<<<4096, blk, 0, stream>>>(H1B, OUTB, CATB);
  gemm_bf16<0,0><<<dim3(1024/128, 4096/128), blk, 0, stream>>>(
      CATB, wfB, bff, FB, nullptr, 4096, 1024, 2048, 1.f);
  ln_relu_final<<<4096, blk, 0, stream>>>(FB, g_f, be_f, out);
}

// Round 3
// 3466.278 us; speedup vs baseline: 8.6761x; 1.5295x over previous
//
#include <hip/hip_runtime.h>
#include <hip/hip_bf16.h>
#include <math.h>

#define B_ 16
#define T_ 256
#define D_ 1024
#define H_ 1024
#define S_ 16
#define SCALE_ (1.0f/32.0f)   // 1/sqrt(1024)

typedef __attribute__((ext_vector_type(8))) short short8v;
typedef __attribute__((ext_vector_type(4))) float f32x4;

__device__ __forceinline__ float sigm(float x) { return 1.f / (1.f + expf(-x)); }

__device__ __forceinline__ ushort f2b(float v) {
  __hip_bfloat16 h = __float2bfloat16(v);
  return *reinterpret_cast<ushort*>(&h);
}
__device__ __forceinline__ float b2f(ushort u) {
  union { unsigned u32; float f; } x; x.u32 = ((unsigned)u) << 16; return x.f;
}

__device__ __forceinline__ void glds16(const void* g, void* l) {
  __builtin_amdgcn_global_load_lds((const __attribute__((address_space(1))) void*)g,
                                   (__attribute__((address_space(3))) void*)l, 16, 0, 0);
}

__device__ __forceinline__ float block_sum256(float v) {
  __shared__ float lds[4];
  #pragma unroll
  for (int off = 32; off; off >>= 1) v += __shfl_down(v, off);
  int w = threadIdx.x >> 6;
  if ((threadIdx.x & 63) == 0) lds[w] = v;
  __syncthreads();
  float r = lds[0] + lds[1] + lds[2] + lds[3];
  __syncthreads();
  return r;
}

// ---------------- fp32 -> bf16 convert ----------------
__global__ __launch_bounds__(256)
void cvt_bf16(const float* __restrict__ in, ushort* __restrict__ out, int n)
{
  int i = (blockIdx.x * 256 + threadIdx.x) * 4;
  if (i >= n) return;
  float4 v = *(const float4*)(in + i);
  ushort4 o; o.x = f2b(v.x); o.y = f2b(v.y); o.z = f2b(v.z); o.w = f2b(v.w);
  *(ushort4*)(out + i) = o;
}

// ---------------- MFMA bf16 GEMM: C = act(ascale * A@W^T + bias) ----------------
template<int ACT, int REMAP>   // ACT: 0 none, 1 relu, 2 sigmoid
__global__ __launch_bounds__(256)
void gemm_bf16(const ushort* __restrict__ A, const ushort* __restrict__ W,
               const float* __restrict__ bias,
               float* __restrict__ Cf, ushort* __restrict__ Cb,
               int M, int N, int K, float ascale)
{
  __shared__ char As[16384];
  __shared__ char Bs[16384];
  const int tid = threadIdx.x;
  const int w = tid >> 6, l = tid & 63;
  const int m0 = blockIdx.y * 128, n0 = blockIdx.x * 128;
  const int wm = w >> 1, wn = w & 1;
  const int srow = l >> 3;
  const int sbyte = ((l & 7) * 16) ^ (srow << 4);
  f32x4 acc[4][4];
  #pragma unroll
  for (int i = 0; i < 4; ++i)
    #pragma unroll
    for (int j = 0; j < 4; ++j) acc[i][j] = (f32x4){0.f, 0.f, 0.f, 0.f};

  for (int k0 = 0; k0 < K; k0 += 64) {
    __syncthreads();
    #pragma unroll
    for (int c = 0; c < 4; ++c) {
      int ca = w * 4 + c;
      int r = ca * 8 + srow;
      glds16((const char*)A + (((size_t)(m0 + r) * K + k0) << 1) + sbyte, As + ca * 1024);
      glds16((const char*)W + (((size_t)(n0 + r) * K + k0) << 1) + sbyte, Bs + ca * 1024);
    }
    __syncthreads();
    #pragma unroll
    for (int ks = 0; ks < 2; ++ks) {
      short8v a[4], b[4];
      int qb = ks * 64 + (l >> 4) * 16;
      #pragma unroll
      for (int i = 0; i < 4; ++i) {
        int ra = wm * 64 + i * 16 + (l & 15);
        a[i] = *(const short8v*)(As + ra * 128 + (qb ^ ((ra & 7) << 4)));
        int rb = wn * 64 + i * 16 + (l & 15);
        b[i] = *(const short8v*)(Bs + rb * 128 + (qb ^ ((rb & 7) << 4)));
      }
      #pragma unroll
      for (int i = 0; i < 4; ++i)
        #pragma unroll
        for (int j = 0; j < 4; ++j)
          acc[i][j] = __builtin_amdgcn_mfma_f32_16x16x32_bf16(a[i], b[j], acc[i][j], 0, 0, 0);
    }
  }
  #pragma unroll
  for (int i = 0; i < 4; ++i) {
    #pragma unroll
    for (int j = 0; j < 4; ++j) {
      int n = n0 + wn * 64 + j * 16 + (l & 15);
      float bv = bias ? bias[n] : 0.f;
      #pragma unroll
      for (int q = 0; q < 4; ++q) {
        int m = m0 + wm * 64 + i * 16 + (l >> 4) * 4 + q;
        float v = acc[i][j][q] * ascale + bv;
        if (ACT == 1) v = fmaxf(v, 0.f);
        if (ACT == 2) v = sigm(v);
        size_t off = REMAP ? ((size_t)((m & 255) * 16 + (m >> 8)) * N + n)
                           : ((size_t)m * N + n);
        if (Cf) Cf[off] = v;
        if (Cb) Cb[off] = f2b(v);
      }
    }
  }
}

// ---------------- LayerNorm+relu: f32 in -> bf16 out ----------------
__global__ __launch_bounds__(256)
void ln_relu_bf16(const float* __restrict__ X, const float* __restrict__ g,
                  const float* __restrict__ be, ushort* __restrict__ out)
{
  size_t row = blockIdx.x;
  const float4* p = (const float4*)(X + row * 1024);
  int tid = threadIdx.x;
  float4 v = p[tid];
  float s = block_sum256(v.x + v.y + v.z + v.w);
  float mean = s * (1.f / 1024.f);
  float dx = v.x - mean, dy = v.y - mean, dz = v.z - mean, dw = v.w - mean;
  float ss = block_sum256(dx*dx + dy*dy + dz*dz + dw*dw);
  float r = rsqrtf(ss * (1.f / 1024.f) + 1e-5f);
  int c4 = tid * 4;
  ushort4 o;
  o.x = f2b(fmaxf(dx * r * g[c4+0] + be[c4+0], 0.f));
  o.y = f2b(fmaxf(dy * r * g[c4+1] + be[c4+1], 0.f));
  o.z = f2b(fmaxf(dz * r * g[c4+2] + be[c4+2], 0.f));
  o.w = f2b(fmaxf(dw * r * g[c4+3] + be[c4+3], 0.f));
  *(ushort4*)(out + row * 1024 + c4) = o;
}

// final LN+relu: rows (t*B+b) f32 -> out [b][t][h] f32
__global__ __launch_bounds__(256)
void ln_relu_final(const float* __restrict__ F, const float* __restrict__ g,
                   const float* __restrict__ be, float* __restrict__ out)
{
  int row = blockIdx.x;           // t*16 + b
  int t = row >> 4, b = row & 15;
  const float4* p = (const float4*)(F + (size_t)row * 1024);
  int tid = threadIdx.x;
  float4 v = p[tid];
  float s = block_sum256(v.x + v.y + v.z + v.w);
  float mean = s * (1.f / 1024.f);
  float dx = v.x - mean, dy = v.y - mean, dz = v.z - mean, dw = v.w - mean;
  float ss = block_sum256(dx*dx + dy*dy + dz*dz + dw*dw);
  float r = rsqrtf(ss * (1.f / 1024.f) + 1e-5f);
  int c4 = tid * 4;
  float4 o;
  o.x = fmaxf(dx * r * g[c4+0] + be[c4+0], 0.f);
  o.y = fmaxf(dy * r * g[c4+1] + be[c4+1], 0.f);
  o.z = fmaxf(dz * r * g[c4+2] + be[c4+2], 0.f);
  o.w = fmaxf(dw * r * g[c4+3] + be[c4+3], 0.f);
  ((float4*)(out + ((size_t)b * T_ + t) * 1024))[tid] = o;
}

// ---------------- fused LSTM pipeline phase ----------------
// 128 blocks x 512 threads. Blocks 0..63: layer-0 step t. Blocks 64..127:
// layer-1 step t-1. The two halves are data-independent within one launch;
// the t-recurrence is carried by stream ordering across launches.
__global__ __launch_bounds__(512)
void lstm_fused_step(const ushort* __restrict__ Z0T,   // [T*B,4096] bf16
                     const ushort* __restrict__ whh0,  // [4096,1024]
                     const float* __restrict__ bhh0,
                     const ushort* __restrict__ wih1,  // [4096,1024]
                     const ushort* __restrict__ whh1,  // [4096,1024]
                     const float* __restrict__ bih1,
                     const float* __restrict__ bhh1,
                     ushort* __restrict__ h0A, ushort* __restrict__ h0B,
                     ushort* __restrict__ h1A, ushort* __restrict__ h1B,
                     float* __restrict__ c0, float* __restrict__ c1,
                     ushort* __restrict__ H1O,         // [T*B,1024] bf16
                     float* __restrict__ KSUM,         // [S*B,1024] f32
                     int t)
{
  __shared__ char Ah[65536];
  __shared__ float zs[8][16][16];
  const int tid = threadIdx.x, w = tid >> 6, l = tid & 63;

  if (blockIdx.x < 64) {
    // ---- layer-0, step t ----
    if (t >= T_) return;
    const ushort* hin = (t & 1) ? h0B : h0A;
    ushort* hout      = (t & 1) ? h0A : h0B;
    #pragma unroll
    for (int it = 0; it < 4; ++it) {
      int g1k = w * 4 + it;             // 1KB chunk 0..31
      int kc = g1k * 4 + (l >> 4);      // 0..127
      int m = (l & 15) ^ (kc & 15);
      glds16((const char*)hin + (((size_t)m * 1024 + kc * 8) << 1), Ah + g1k * 1024);
    }
    __syncthreads();
    const int g = w & 3, kh = w >> 2;
    const int j0 = blockIdx.x * 16;
    const int n = g * 1024 + j0 + (l & 15);
    const ushort* wrow = whh0 + (size_t)n * 1024 + kh * 512;
    f32x4 acc = (f32x4){0.f, 0.f, 0.f, 0.f};
    #pragma unroll
    for (int ks = 0; ks < 16; ++ks) {
      short8v bfrag = *(const short8v*)(wrow + ks * 32 + (l >> 4) * 8);
      int kc = kh * 64 + ks * 4 + (l >> 4);
      short8v afrag = *(const short8v*)(Ah + kc * 256 + (((l & 15) ^ (kc & 15)) << 4));
      acc = __builtin_amdgcn_mfma_f32_16x16x32_bf16(afrag, bfrag, acc, 0, 0, 0);
    }
    #pragma unroll
    for (int q = 0; q < 4; ++q)
      zs[kh * 4 + g][(l >> 4) * 4 + q][l & 15] = acc[q];
    __syncthreads();
    if (tid < 256) {
      int b = tid >> 4, jj = tid & 15, jf = j0 + jj;
      const size_t zrow = ((size_t)t * 16 + b) * 4096;
      float zi = zs[0][b][jj] + zs[4][b][jj] + b2f(Z0T[zrow + jf])        + bhh0[jf];
      float zf = zs[1][b][jj] + zs[5][b][jj] + b2f(Z0T[zrow + 1024 + jf]) + bhh0[1024 + jf];
      float zg = zs[2][b][jj] + zs[6][b][jj] + b2f(Z0T[zrow + 2048 + jf]) + bhh0[2048 + jf];
      float zo = zs[3][b][jj] + zs[7][b][jj] + b2f(Z0T[zrow + 3072 + jf]) + bhh0[3072 + jf];
      float cp = sigm(zf) * c0[b * 1024 + jf] + sigm(zi) * tanhf(zg);
      c0[b * 1024 + jf] = cp;
      hout[b * 1024 + jf] = f2b(sigm(zo) * tanhf(cp));
    }
  } else {
    // ---- layer-1, step s = t-1 ----
    if (t == 0) return;
    const int s = t - 1;
    const ushort* h0new = (s & 1) ? h0A : h0B;   // layer-0 output of step s
    const ushort* h1in  = (s & 1) ? h1B : h1A;
    ushort* h1out       = (s & 1) ? h1A : h1B;
    #pragma unroll
    for (int it = 0; it < 8; ++it) {
      int g1k = w * 8 + it;             // 0..63
      int kc = g1k * 4 + (l >> 4);      // 0..255
      int m = (l & 15) ^ (kc & 15);
      const char* src = (kc < 128)
        ? (const char*)h0new + (((size_t)m * 1024 + kc * 8) << 1)
        : (const char*)h1in  + (((size_t)m * 1024 + (kc - 128) * 8) << 1);
      glds16(src, Ah + g1k * 1024);
    }
    __syncthreads();
    const int g = w & 3, kh = w >> 2;
    const int j0 = (blockIdx.x - 64) * 16;
    const int n = g * 1024 + j0 + (l & 15);
    const ushort* wrow = (kh ? whh1 : wih1) + (size_t)n * 1024;
    f32x4 acc = (f32x4){0.f, 0.f, 0.f, 0.f};
    #pragma unroll
    for (int ks = 0; ks < 32; ++ks) {
      short8v bfrag = *(const short8v*)(wrow + ks * 32 + (l >> 4) * 8);
      int kc = kh * 128 + ks * 4 + (l >> 4);
      short8v afrag = *(const short8v*)(Ah + kc * 256 + (((l & 15) ^ (kc & 15)) << 4));
      acc = __builtin_amdgcn_mfma_f32_16x16x32_bf16(afrag, bfrag, acc, 0, 0, 0);
    }
    #pragma unroll
    for (int q = 0; q < 4; ++q)
      zs[kh * 4 + g][(l >> 4) * 4 + q][l & 15] = acc[q];
    __syncthreads();
    if (tid < 256) {
      int b = tid >> 4, jj = tid & 15, jf = j0 + jj;
      float zi = zs[0][b][jj] + zs[4][b][jj] + bih1[jf]        + bhh1[jf];
      float zf = zs[1][b][jj] + zs[5][b][jj] + bih1[1024 + jf] + bhh1[1024 + jf];
      float zg = zs[2][b][jj] + zs[6][b][jj] + bih1[2048 + jf] + bhh1[2048 + jf];
      float zo = zs[3][b][jj] + zs[7][b][jj] + bih1[3072 + jf] + bhh1[3072 + jf];
      float cp = sigm(zf) * c1[b * 1024 + jf] + sigm(zi) * tanhf(zg);
      c1[b * 1024 + jf] = cp;
      float hv = sigm(zo) * tanhf(cp);
      ushort hb = f2b(hv);
      h1out[b * 1024 + jf] = hb;
      H1O[((size_t)s * 16 + b) * 1024 + jf] = hb;
      KSUM[((size_t)(s >> 4) * 16 + b) * 1024 + jf] += hv;
    }
  }
}

// gather segment-final h1 rows (bf16) into VINB [S*B, H]
__global__ __launch_bounds__(256)
void vgather(const ushort* __restrict__ H1B, ushort* __restrict__ VINB)
{
  int i = blockIdx.x * 256 + threadIdx.x;
  int row = i >> 8, c4 = (i & 255) * 4;
  int src = (row >> 4) * 256 + 240 + (row & 15);
  *(ushort4*)(VINB + (size_t)row * 1024 + c4) =
      *(const ushort4*)(H1B + (size_t)src * 1024 + c4);
}

// per-(b,t) masked softmax attention over cached segments (all f32)
__global__ __launch_bounds__(256)
void attn_kernel(const float* __restrict__ Q, const float* __restrict__ kbank,
                 const float* __restrict__ vbank, float* __restrict__ R)
{
  int row = blockIdx.x;          // t*16 + b
  int t = row >> 4, b = row & 15;
  int si = t >> 4;
  int tid = threadIdx.x, lane = tid & 63, w = tid >> 6;
  if (si == 0) {
    float4 z = {0.f, 0.f, 0.f, 0.f};
    ((float4*)(R + (size_t)row * 1024))[tid] = z;
    return;
  }
  __shared__ float sc[16];
  const float* q = Q + (size_t)row * 1024;
  for (int s = w; s < si; s += 4) {
    const float* kk = kbank + ((size_t)s * 16 + b) * 1024;
    float p = 0.f;
    for (int k = lane; k < 1024; k += 64) p += q[k] * kk[k];
    #pragma unroll
    for (int off = 32; off; off >>= 1) p += __shfl_down(p, off);
    if (lane == 0) sc[s] = p * SCALE_;
  }
  __syncthreads();
  float mx = -1e30f;
  for (int s = 0; s < si; ++s) mx = fmaxf(mx, sc[s]);
  float den = 0.f;
  for (int s = 0; s < si; ++s) den += expf(sc[s] - mx);
  float inv = 1.f / den;
  float4 accv = {0.f, 0.f, 0.f, 0.f};
  for (int s = 0; s < si; ++s) {
    float a = expf(sc[s] - mx) * inv;
    float4 vv = ((const float4*)(vbank + ((size_t)s * 16 + b) * 1024))[tid];
    accv.x += a * vv.x; accv.y += a * vv.y; accv.z += a * vv.z; accv.w += a * vv.w;
  }
  ((float4*)(R + (size_t)row * 1024))[tid] = accv;
}

// GI = [h1, R, h1-R] bf16, K=3072
__global__ __launch_bounds__(256)
void build_gi(const ushort* __restrict__ H1B, const float* __restrict__ R,
              ushort* __restrict__ GI)
{
  size_t r = blockIdx.x;
  int c4 = threadIdx.x * 4;
  ushort4 h4 = *(const ushort4*)(H1B + r * 1024 + c4);
  float4 rv = *(const float4*)(R + r * 1024 + c4);
  *(ushort4*)(GI + r * 3072 + c4) = h4;
  ushort4 rb; rb.x = f2b(rv.x); rb.y = f2b(rv.y); rb.z = f2b(rv.z); rb.w = f2b(rv.w);
  *(ushort4*)(GI + r * 3072 + 1024 + c4) = rb;
  ushort4 d;
  d.x = f2b(b2f(h4.x) - rv.x); d.y = f2b(b2f(h4.y) - rv.y);
  d.z = f2b(b2f(h4.z) - rv.z); d.w = f2b(b2f(h4.w) - rv.w);
  *(ushort4*)(GI + r * 3072 + 2048 + c4) = d;
}

// mix = gate*h1 + (1-gate)*R  -> bf16
__global__ __launch_bounds__(256)
void build_mix(const float* __restrict__ G, const ushort* __restrict__ H1B,
               const float* __restrict__ R, ushort* __restrict__ M)
{
  size_t r = blockIdx.x;
  int c4 = threadIdx.x * 4;
  float4 g = *(const float4*)(G + r * 1024 + c4);
  ushort4 h = *(const ushort4*)(H1B + r * 1024 + c4);
  float4 rv = *(const float4*)(R + r * 1024 + c4);
  ushort4 o;
  o.x = f2b(g.x * b2f(h.x) + (1.f - g.x) * rv.x);
  o.y = f2b(g.y * b2f(h.y) + (1.f - g.y) * rv.y);
  o.z = f2b(g.z * b2f(h.z) + (1.f - g.z) * rv.z);
  o.w = f2b(g.w * b2f(h.w) + (1.f - g.w) * rv.w);
  *(ushort4*)(M + r * 1024 + c4) = o;
}

// CAT = [h1, (t>=16 ? out : 0)] bf16, K=2048
__global__ __launch_bounds__(256)
void build_cat(const ushort* __restrict__ H1B, const float* __restrict__ O,
               ushort* __restrict__ C)
{
  size_t r = blockIdx.x;
  int c4 = threadIdx.x * 4;
  *(ushort4*)(C + r * 2048 + c4) = *(const ushort4*)(H1B + r * 1024 + c4);
  ushort4 o;
  if (r >= 256) {
    float4 v = *(const float4*)(O + r * 1024 + c4);
    o.x = f2b(v.x); o.y = f2b(v.y); o.z = f2b(v.z); o.w = f2b(v.w);
  } else { o.x = o.y = o.z = o.w = 0; }
  *(ushort4*)(C + r * 2048 + 1024 + c4) = o;
}

extern "C" void kernel_launch(void* const* d_in, const int* in_sizes, int n_in,
                              void* d_out, int out_size, void* d_ws, size_t ws_size,
                              hipStream_t stream) {
  const float* x     = (const float*)d_in[0];
  const float* W_ip  = (const float*)d_in[1];
  const float* b_ip  = (const float*)d_in[2];
  const float* g_ip  = (const float*)d_in[3];
  const float* be_ip = (const float*)d_in[4];
  const float* W_ih0 = (const float*)d_in[5];
  const float* W_hh0 = (const float*)d_in[6];
  const float* b_ih0 = (const float*)d_in[7];
  const float* b_hh0 = (const float*)d_in[8];
  const float* W_ih1 = (const float*)d_in[9];
  const float* W_hh1 = (const float*)d_in[10];
  const float* b_ih1 = (const float*)d_in[11];
  const float* b_hh1 = (const float*)d_in[12];
  const float* Wq    = (const float*)d_in[13];
  const float* Wk    = (const float*)d_in[14];
  const float* Wv    = (const float*)d_in[15];
  const float* Wg1   = (const float*)d_in[16];
  const float* bg1   = (const float*)d_in[17];
  const float* Wg2   = (const float*)d_in[18];
  const float* bg2   = (const float*)d_in[19];
  const float* Wo    = (const float*)d_in[20];
  const float* bo    = (const float*)d_in[21];
  const float* Wf    = (const float*)d_in[22];
  const float* bff   = (const float*)d_in[23];
  const float* g_f   = (const float*)d_in[24];
  const float* be_f  = (const float*)d_in[25];
  float* out = (float*)d_out;
  char* ws = (char*)d_ws;
  const size_t MB = (size_t)1 << 20;
  const size_t KB = (size_t)1 << 10;

  // bf16 weight pool (offsets in elements)
  ushort* WB = (ushort*)(ws);
  ushort* wipB  = WB;             // 1M
  ushort* wih0B = WB + 1*1048576; // 4M
  ushort* whh0B = WB + 5*1048576;
  ushort* wih1B = WB + 9*1048576;
  ushort* whh1B = WB + 13*1048576;
  ushort* wqB   = WB + 17*1048576;
  ushort* wkB   = WB + 18*1048576;
  ushort* wvB   = WB + 19*1048576;
  ushort* wg1B  = WB + 20*1048576; // 3M
  ushort* wg2B  = WB + 23*1048576;
  ushort* woB   = WB + 24*1048576;
  ushort* wfB   = WB + 25*1048576; // 2M -> ends 27M elems = 54MB

  ushort* XB   = (ushort*)(ws + 54 * MB);   // 8MB: x bf16, later XPB
  float*  XP   = (float*)(ws + 62 * MB);    // 16MB: input_proj pre-LN, later Q
  float*  Qf   = XP;
  char*   SCR  = ws + 78 * MB;              // 48MB scratch region
  ushort* Z0T  = (ushort*)SCR;              // 32MB bf16 [T*B,4096]
  ushort* GIB  = (ushort*)SCR;              // 24MB (after loop)
  ushort* G1B  = (ushort*)(SCR + 24 * MB);  // 8MB
  float*  GT   = (float*)(SCR + 32 * MB);   // 16MB
  ushort* MIXB = (ushort*)SCR;              // 8MB
  float*  OUTB = (float*)(SCR + 8 * MB);    // 16MB
  ushort* CATB = (ushort*)(SCR + 24 * MB);  // 16MB
  float*  FB   = (float*)SCR;               // 16MB
  ushort* H1B  = (ushort*)(ws + 126 * MB);  // 8MB
  float*  R    = (float*)(ws + 134 * MB);   // 16MB
  char*   ST   = ws + 150 * MB;
  ushort* h0Ba = (ushort*)(ST);
  ushort* h0Bb = (ushort*)(ST + 32 * KB);
  ushort* h1Ba = (ushort*)(ST + 64 * KB);
  ushort* h1Bb = (ushort*)(ST + 96 * KB);
  float*  c0   = (float*)(ST + 128 * KB);
  float*  c1   = (float*)(ST + 192 * KB);
  float*  KSUM = (float*)(ST + 256 * KB);         // 1MB
  ushort* KSB  = (ushort*)(ST + 1280 * KB);       // 0.5MB
  float*  KBf  = (float*)(ST + 1792 * KB);        // 1MB
  float*  VBf  = (float*)(ST + 2816 * KB);        // 1MB
  ushort* VINB = (ushort*)(ST + 3840 * KB);       // 0.5MB

  // zero recurrent state + KSUM
  hipMemsetAsync(ST, 0, 1280 * KB, stream);

  dim3 blk(256);
  auto cvt = [&](const float* src, ushort* dst, int n) {
    cvt_bf16<<<dim3((n / 4 + 255) / 256), blk, 0, stream>>>(src, dst, n);
  };
  // weight + input conversions
  cvt(x,     XB,    4194304);
  cvt(W_ip,  wipB,  1048576);
  cvt(W_ih0, wih0B, 4194304);
  cvt(W_hh0, whh0B, 4194304);
  cvt(W_ih1, wih1B, 4194304);
  cvt(W_hh1, whh1B, 4194304);
  cvt(Wq,    wqB,   1048576);
  cvt(Wk,    wkB,   1048576);
  cvt(Wv,    wvB,   1048576);
  cvt(Wg1,   wg1B,  3145728);
  cvt(Wg2,   wg2B,  1048576);
  cvt(Wo,    woB,   1048576);
  cvt(Wf,    wfB,   2097152);

  // Phase A: XP = x@W_ip^T + b_ip ; XPB = relu(LN(XP)) (bf16, stored in XB space)
  gemm_bf16<0,0><<<dim3(1024/128, 4096/128), blk, 0, stream>>>(
      XB, wipB, b_ip, XP, nullptr, 4096, 1024, 1024, 1.f);
  ln_relu_bf16<<<4096, blk, 0, stream>>>(XP, g_ip, be_ip, XB);
  // Phase B: Z0T = XPB@W_ih0^T + b_ih0, rows remapped to t*16+b, bf16
  gemm_bf16<0,1><<<dim3(4096/128, 4096/128), blk, 0, stream>>>(
      XB, wih0B, b_ih0, nullptr, Z0T, 4096, 4096, 1024, 1.f);
  // Phase C: 257 pipelined phases, one launch each:
  //   launch t runs L0(t) on blocks 0..63 and L1(t-1) on blocks 64..127.
  dim3 blk512(512);
  for (int t = 0; t <= T_; ++t) {
    lstm_fused_step<<<128, blk512, 0, stream>>>(
        Z0T, whh0B, b_hh0, wih1B, whh1B, b_ih1, b_hh1,
        h0Ba, h0Bb, h1Ba, h1Bb, c0, c1, H1B, KSUM, t);
  }
  // Phase D: kbank / vbank
  cvt(KSUM, KSB, 262144);
  gemm_bf16<0,0><<<dim3(1024/128, 256/128), blk, 0, stream>>>(
      KSB, wkB, nullptr, KBf, nullptr, 256, 1024, 1024, 1.f/16.f);
  vgather<<<256, blk, 0, stream>>>(H1B, VINB);
  gemm_bf16<0,0><<<dim3(1024/128, 256/128), blk, 0, stream>>>(
      VINB, wvB, nullptr, VBf, nullptr, 256, 1024, 1024, 1.f);
  // Phase E: retrieval + gate + output
  gemm_bf16<0,0><<<dim3(1024/128, 4096/128), blk, 0, stream>>>(
      H1B, wqB, nullptr, Qf, nullptr, 4096, 1024, 1024, 1.f);
  attn_kernel<<<4096, blk, 0, stream>>>(Qf, KBf, VBf, R);
  build_gi<<<4096, blk, 0, stream>>>(H1B, R, GIB);
  gemm_bf16<1,0><<<dim3(1024/128, 4096/128), blk, 0, stream>>>(
      GIB, wg1B, bg1, nullptr, G1B, 4096, 1024, 3072, 1.f);
  gemm_bf16<2,0><<<dim3(1024/128, 4096/128), blk, 0, stream>>>(
      G1B, wg2B, bg2, GT, nullptr, 4096, 1024, 1024, 1.f);
  build_mix<<<4096, blk, 0, stream>>>(GT, H1B, R, MIXB);
  gemm_bf16<0,0><<<dim3(1024/128, 4096/128), blk, 0, stream>>>(
      MIXB, woB, bo, OUTB, nullptr, 4096, 1024, 1024, 1.f);
  build_cat<<<4096, blk, 0, stream>>>(H1B, OUTB, CATB);
  gemm_bf16<0,0><<<dim3(1024/128, 4096/128), blk, 0, stream>>>(
      CATB, wfB, bff, FB, nullptr, 4096, 1024, 2048, 1.f);
  ln_relu_final<<<4096, blk, 0, stream>>>(FB, g_f, be_f, out);
}

// Round 4
// 2235.509 us; speedup vs baseline: 13.4528x; 1.5506x over previous
//
#include <hip/hip_runtime.h>
#include <hip/hip_bf16.h>
#include <math.h>

#define B_ 16
#define T_ 256
#define D_ 1024
#define H_ 1024
#define S_ 16
#define SCALE_ (1.0f/32.0f)   // 1/sqrt(1024)

typedef __attribute__((ext_vector_type(8))) short short8v;
typedef __attribute__((ext_vector_type(4))) float f32x4;

__device__ __forceinline__ float sigm(float x) { return 1.f / (1.f + expf(-x)); }

__device__ __forceinline__ ushort f2b(float v) {
  __hip_bfloat16 h = __float2bfloat16(v);
  return *reinterpret_cast<ushort*>(&h);
}
__device__ __forceinline__ float b2f(ushort u) {
  union { unsigned u32; float f; } x; x.u32 = ((unsigned)u) << 16; return x.f;
}

__device__ __forceinline__ void glds16(const void* g, void* l) {
  __builtin_amdgcn_global_load_lds((const __attribute__((address_space(1))) void*)g,
                                   (__attribute__((address_space(3))) void*)l, 16, 0, 0);
}

__device__ __forceinline__ void waitflag(int* f, int target) {
  while (__hip_atomic_load(f, __ATOMIC_ACQUIRE, __HIP_MEMORY_SCOPE_AGENT) < target)
    __builtin_amdgcn_s_sleep(2);
}

__device__ __forceinline__ float block_sum256(float v) {
  __shared__ float lds[4];
  #pragma unroll
  for (int off = 32; off; off >>= 1) v += __shfl_down(v, off);
  int w = threadIdx.x >> 6;
  if ((threadIdx.x & 63) == 0) lds[w] = v;
  __syncthreads();
  float r = lds[0] + lds[1] + lds[2] + lds[3];
  __syncthreads();
  return r;
}

// ---------------- fp32 -> bf16 convert ----------------
__global__ __launch_bounds__(256)
void cvt_bf16(const float* __restrict__ in, ushort* __restrict__ out, int n)
{
  int i = (blockIdx.x * 256 + threadIdx.x) * 4;
  if (i >= n) return;
  float4 v = *(const float4*)(in + i);
  ushort4 o; o.x = f2b(v.x); o.y = f2b(v.y); o.z = f2b(v.z); o.w = f2b(v.w);
  *(ushort4*)(out + i) = o;
}

// ---------------- MFMA bf16 GEMM: C = act(ascale * A@W^T + bias) ----------------
template<int ACT, int REMAP>   // ACT: 0 none, 1 relu, 2 sigmoid
__global__ __launch_bounds__(256)
void gemm_bf16(const ushort* __restrict__ A, const ushort* __restrict__ W,
               const float* __restrict__ bias,
               float* __restrict__ Cf, ushort* __restrict__ Cb,
               int M, int N, int K, float ascale)
{
  __shared__ char As[16384];
  __shared__ char Bs[16384];
  const int tid = threadIdx.x;
  const int w = tid >> 6, l = tid & 63;
  const int m0 = blockIdx.y * 128, n0 = blockIdx.x * 128;
  const int wm = w >> 1, wn = w & 1;
  const int srow = l >> 3;
  const int sbyte = ((l & 7) * 16) ^ (srow << 4);
  f32x4 acc[4][4];
  #pragma unroll
  for (int i = 0; i < 4; ++i)
    #pragma unroll
    for (int j = 0; j < 4; ++j) acc[i][j] = (f32x4){0.f, 0.f, 0.f, 0.f};

  for (int k0 = 0; k0 < K; k0 += 64) {
    __syncthreads();
    #pragma unroll
    for (int c = 0; c < 4; ++c) {
      int ca = w * 4 + c;
      int r = ca * 8 + srow;
      glds16((const char*)A + (((size_t)(m0 + r) * K + k0) << 1) + sbyte, As + ca * 1024);
      glds16((const char*)W + (((size_t)(n0 + r) * K + k0) << 1) + sbyte, Bs + ca * 1024);
    }
    __syncthreads();
    #pragma unroll
    for (int ks = 0; ks < 2; ++ks) {
      short8v a[4], b[4];
      int qb = ks * 64 + (l >> 4) * 16;
      #pragma unroll
      for (int i = 0; i < 4; ++i) {
        int ra = wm * 64 + i * 16 + (l & 15);
        a[i] = *(const short8v*)(As + ra * 128 + (qb ^ ((ra & 7) << 4)));
        int rb = wn * 64 + i * 16 + (l & 15);
        b[i] = *(const short8v*)(Bs + rb * 128 + (qb ^ ((rb & 7) << 4)));
      }
      #pragma unroll
      for (int i = 0; i < 4; ++i)
        #pragma unroll
        for (int j = 0; j < 4; ++j)
          acc[i][j] = __builtin_amdgcn_mfma_f32_16x16x32_bf16(a[i], b[j], acc[i][j], 0, 0, 0);
    }
  }
  #pragma unroll
  for (int i = 0; i < 4; ++i) {
    #pragma unroll
    for (int j = 0; j < 4; ++j) {
      int n = n0 + wn * 64 + j * 16 + (l & 15);
      float bv = bias ? bias[n] : 0.f;
      #pragma unroll
      for (int q = 0; q < 4; ++q) {
        int m = m0 + wm * 64 + i * 16 + (l >> 4) * 4 + q;
        float v = acc[i][j][q] * ascale + bv;
        if (ACT == 1) v = fmaxf(v, 0.f);
        if (ACT == 2) v = sigm(v);
        size_t off = REMAP ? ((size_t)((m & 255) * 16 + (m >> 8)) * N + n)
                           : ((size_t)m * N + n);
        if (Cf) Cf[off] = v;
        if (Cb) Cb[off] = f2b(v);
      }
    }
  }
}

// ---------------- LayerNorm+relu: f32 in -> bf16 out ----------------
__global__ __launch_bounds__(256)
void ln_relu_bf16(const float* __restrict__ X, const float* __restrict__ g,
                  const float* __restrict__ be, ushort* __restrict__ out)
{
  size_t row = blockIdx.x;
  const float4* p = (const float4*)(X + row * 1024);
  int tid = threadIdx.x;
  float4 v = p[tid];
  float s = block_sum256(v.x + v.y + v.z + v.w);
  float mean = s * (1.f / 1024.f);
  float dx = v.x - mean, dy = v.y - mean, dz = v.z - mean, dw = v.w - mean;
  float ss = block_sum256(dx*dx + dy*dy + dz*dz + dw*dw);
  float r = rsqrtf(ss * (1.f / 1024.f) + 1e-5f);
  int c4 = tid * 4;
  ushort4 o;
  o.x = f2b(fmaxf(dx * r * g[c4+0] + be[c4+0], 0.f));
  o.y = f2b(fmaxf(dy * r * g[c4+1] + be[c4+1], 0.f));
  o.z = f2b(fmaxf(dz * r * g[c4+2] + be[c4+2], 0.f));
  o.w = f2b(fmaxf(dw * r * g[c4+3] + be[c4+3], 0.f));
  *(ushort4*)(out + row * 1024 + c4) = o;
}

// final LN+relu: rows (t*B+b) f32 -> out [b][t][h] f32
__global__ __launch_bounds__(256)
void ln_relu_final(const float* __restrict__ F, const float* __restrict__ g,
                   const float* __restrict__ be, float* __restrict__ out)
{
  int row = blockIdx.x;           // t*16 + b
  int t = row >> 4, b = row & 15;
  const float4* p = (const float4*)(F + (size_t)row * 1024);
  int tid = threadIdx.x;
  float4 v = p[tid];
  float s = block_sum256(v.x + v.y + v.z + v.w);
  float mean = s * (1.f / 1024.f);
  float dx = v.x - mean, dy = v.y - mean, dz = v.z - mean, dw = v.w - mean;
  float ss = block_sum256(dx*dx + dy*dy + dz*dz + dw*dw);
  float r = rsqrtf(ss * (1.f / 1024.f) + 1e-5f);
  int c4 = tid * 4;
  float4 o;
  o.x = fmaxf(dx * r * g[c4+0] + be[c4+0], 0.f);
  o.y = fmaxf(dy * r * g[c4+1] + be[c4+1], 0.f);
  o.z = fmaxf(dz * r * g[c4+2] + be[c4+2], 0.f);
  o.w = fmaxf(dw * r * g[c4+3] + be[c4+3], 0.f);
  ((float4*)(out + ((size_t)b * T_ + t) * 1024))[tid] = o;
}

// ---------------- persistent cooperative LSTM (all 256 steps) ----------------
// 128 blocks x 512 threads, cooperative launch (co-residency guaranteed).
// Blocks 0..63: layer 0, block jb owns output cols j0..j0+15 (all 4 gates).
// Blocks 64..127: layer 1, same column ownership.
// Weights live in VGPRs (preloaded once). c-state/bias/KSUM in registers.
// Cross-block dataflow: per-step write-once h buffers + ready counters.
// h stores are agent-scope (sc1 -> LLC, coherent across XCDs); flags are
// RELEASE/ACQUIRE agent atomics. Flags zeroed by in-stream memset per call.
__global__ __launch_bounds__(512)
void lstm_persistent(const ushort* __restrict__ Z0T,   // [T*B,4096] bf16
                     const ushort* __restrict__ whh0,  // [4096,1024]
                     const float* __restrict__ bhh0,
                     const ushort* __restrict__ wih1,  // [4096,1024]
                     const ushort* __restrict__ whh1,  // [4096,1024]
                     const float* __restrict__ bih1,
                     const float* __restrict__ bhh1,
                     ushort* __restrict__ HP,          // [257][16][1024], slot0 zeroed
                     ushort* __restrict__ H1B,         // [256][16][1024]
                     const ushort* __restrict__ ZP,    // 32KB zeros (h1 at t=-1)
                     float* __restrict__ KSUM,         // [S*B,1024] f32
                     int* flag0, int* flag1)
{
  __shared__ char Ah[65536];
  __shared__ float zs[8][16][16];
  const int tid = threadIdx.x, w = tid >> 6, l = tid & 63;
  const int lm = l & 15, lq = l >> 4;
  const int g = w & 3, kh = w >> 2;
  const int j0 = (blockIdx.x & 63) * 16;
  const int eb = tid >> 4, ej = tid & 15, jf = j0 + ej;   // tid<256 only
  float creg = 0.f;
  float br[4];

  if (blockIdx.x < 64) {
    // ================= layer 0 =================
    short8v wreg[16];
    {
      const int n = g * 1024 + j0 + lm;
      const ushort* wb = whh0 + (size_t)n * 1024 + kh * 512 + lq * 8;
      #pragma unroll
      for (int ks = 0; ks < 16; ++ks) wreg[ks] = *(const short8v*)(wb + ks * 32);
    }
    if (tid < 256) {
      #pragma unroll
      for (int gg = 0; gg < 4; ++gg) br[gg] = bhh0[gg * 1024 + jf];
    }
    for (int t = 0; t < T_; ++t) {
      // prefetch Z0 gate pre-activations (static data) before the spin
      float z0v[4];
      if (tid < 256) {
        const ushort* zp = Z0T + ((size_t)t * 16 + eb) * 4096 + jf;
        #pragma unroll
        for (int gg = 0; gg < 4; ++gg) z0v[gg] = b2f(zp[gg * 1024]);
      }
      if (t > 0) {
        if (tid == 0) waitflag(flag0 + t, 64);
        __syncthreads();
      }
      const ushort* hin = HP + (size_t)t * 16384;
      #pragma unroll
      for (int it = 0; it < 4; ++it) {
        int g1k = w * 4 + it;             // 0..31 (1KB chunks)
        int kc = g1k * 4 + lq;            // 0..127
        int m = lm ^ (kc & 15);
        glds16(hin + (size_t)m * 1024 + kc * 8, Ah + g1k * 1024);
      }
      __syncthreads();
      {
        f32x4 a0 = {0.f,0.f,0.f,0.f}, a1 = {0.f,0.f,0.f,0.f};
        #pragma unroll
        for (int ks = 0; ks < 16; ks += 2) {
          int kc0 = kh * 64 + ks * 4 + lq;
          int kc1 = kc0 + 4;
          short8v f0 = *(const short8v*)(Ah + kc0 * 256 + ((lm ^ (kc0 & 15)) << 4));
          short8v f1 = *(const short8v*)(Ah + kc1 * 256 + ((lm ^ (kc1 & 15)) << 4));
          a0 = __builtin_amdgcn_mfma_f32_16x16x32_bf16(f0, wreg[ks],     a0, 0, 0, 0);
          a1 = __builtin_amdgcn_mfma_f32_16x16x32_bf16(f1, wreg[ks + 1], a1, 0, 0, 0);
        }
        #pragma unroll
        for (int q = 0; q < 4; ++q) zs[w][lq * 4 + q][lm] = a0[q] + a1[q];
      }
      __syncthreads();
      if (tid < 256) {
        float zi = zs[0][eb][ej] + zs[4][eb][ej] + z0v[0] + br[0];
        float zf = zs[1][eb][ej] + zs[5][eb][ej] + z0v[1] + br[1];
        float zg = zs[2][eb][ej] + zs[6][eb][ej] + z0v[2] + br[2];
        float zo = zs[3][eb][ej] + zs[7][eb][ej] + z0v[3] + br[3];
        float cp = sigm(zf) * creg + sigm(zi) * tanhf(zg);
        creg = cp;
        ushort hb = f2b(sigm(zo) * tanhf(cp));
        __hip_atomic_store(HP + (size_t)(t + 1) * 16384 + eb * 1024 + jf, hb,
                           __ATOMIC_RELAXED, __HIP_MEMORY_SCOPE_AGENT);
      }
      __syncthreads();   // drains the h stores (vmcnt 0) for the whole block
      if (tid == 0)
        __hip_atomic_fetch_add(flag0 + t + 1, 1, __ATOMIC_RELEASE, __HIP_MEMORY_SCOPE_AGENT);
    }
  } else {
    // ================= layer 1 =================
    short8v wreg[32];
    {
      const int n = g * 1024 + j0 + lm;
      const ushort* wb = (kh ? whh1 : wih1) + (size_t)n * 1024 + lq * 8;
      #pragma unroll
      for (int ks = 0; ks < 32; ++ks) wreg[ks] = *(const short8v*)(wb + ks * 32);
    }
    if (tid < 256) {
      #pragma unroll
      for (int gg = 0; gg < 4; ++gg)
        br[gg] = bih1[gg * 1024 + jf] + bhh1[gg * 1024 + jf];
    }
    float ksr = 0.f;
    for (int t = 0; t < T_; ++t) {
      if (tid == 0) {
        waitflag(flag0 + t + 1, 64);               // h0 output of step t ready
        if (t > 0) waitflag(flag1 + t - 1, 64);    // h1(t-1) ready
      }
      __syncthreads();
      const ushort* h0n = HP + (size_t)(t + 1) * 16384;
      const ushort* h1p = (t > 0) ? (H1B + (size_t)(t - 1) * 16384) : ZP;
      #pragma unroll
      for (int it = 0; it < 8; ++it) {
        int g1k = w * 8 + it;             // 0..63
        int kc = g1k * 4 + lq;            // 0..255
        int m = lm ^ (kc & 15);
        const ushort* src = (kc < 128)
          ? (h0n + (size_t)m * 1024 + kc * 8)
          : (h1p + (size_t)m * 1024 + (kc - 128) * 8);
        glds16(src, Ah + g1k * 1024);
      }
      __syncthreads();
      {
        f32x4 a0 = {0.f,0.f,0.f,0.f}, a1 = {0.f,0.f,0.f,0.f};
        #pragma unroll
        for (int ks = 0; ks < 32; ks += 2) {
          int kc0 = kh * 128 + ks * 4 + lq;
          int kc1 = kc0 + 4;
          short8v f0 = *(const short8v*)(Ah + kc0 * 256 + ((lm ^ (kc0 & 15)) << 4));
          short8v f1 = *(const short8v*)(Ah + kc1 * 256 + ((lm ^ (kc1 & 15)) << 4));
          a0 = __builtin_amdgcn_mfma_f32_16x16x32_bf16(f0, wreg[ks],     a0, 0, 0, 0);
          a1 = __builtin_amdgcn_mfma_f32_16x16x32_bf16(f1, wreg[ks + 1], a1, 0, 0, 0);
        }
        #pragma unroll
        for (int q = 0; q < 4; ++q) zs[w][lq * 4 + q][lm] = a0[q] + a1[q];
      }
      __syncthreads();
      if (tid < 256) {
        float zi = zs[0][eb][ej] + zs[4][eb][ej] + br[0];
        float zf = zs[1][eb][ej] + zs[5][eb][ej] + br[1];
        float zg = zs[2][eb][ej] + zs[6][eb][ej] + br[2];
        float zo = zs[3][eb][ej] + zs[7][eb][ej] + br[3];
        float cp = sigm(zf) * creg + sigm(zi) * tanhf(zg);
        creg = cp;
        float hv = sigm(zo) * tanhf(cp);
        ksr += hv;
        __hip_atomic_store(H1B + (size_t)t * 16384 + eb * 1024 + jf, f2b(hv),
                           __ATOMIC_RELAXED, __HIP_MEMORY_SCOPE_AGENT);
        if ((t & 15) == 15) {
          KSUM[((size_t)(t >> 4) * 16 + eb) * 1024 + jf] = ksr;   // post-kernel consumer
          ksr = 0.f;
        }
      }
      __syncthreads();
      if (tid == 0)
        __hip_atomic_fetch_add(flag1 + t, 1, __ATOMIC_RELEASE, __HIP_MEMORY_SCOPE_AGENT);
    }
  }
}

// gather segment-final h1 rows (bf16) into VINB [S*B, H]
__global__ __launch_bounds__(256)
void vgather(const ushort* __restrict__ H1B, ushort* __restrict__ VINB)
{
  int i = blockIdx.x * 256 + threadIdx.x;
  int row = i >> 8, c4 = (i & 255) * 4;
  int src = (row >> 4) * 256 + 240 + (row & 15);
  *(ushort4*)(VINB + (size_t)row * 1024 + c4) =
      *(const ushort4*)(H1B + (size_t)src * 1024 + c4);
}

// per-(b,t) masked softmax attention over cached segments (all f32)
__global__ __launch_bounds__(256)
void attn_kernel(const float* __restrict__ Q, const float* __restrict__ kbank,
                 const float* __restrict__ vbank, float* __restrict__ R)
{
  int row = blockIdx.x;          // t*16 + b
  int t = row >> 4, b = row & 15;
  int si = t >> 4;
  int tid = threadIdx.x, lane = tid & 63, w = tid >> 6;
  if (si == 0) {
    float4 z = {0.f, 0.f, 0.f, 0.f};
    ((float4*)(R + (size_t)row * 1024))[tid] = z;
    return;
  }
  __shared__ float sc[16];
  const float* q = Q + (size_t)row * 1024;
  for (int s = w; s < si; s += 4) {
    const float* kk = kbank + ((size_t)s * 16 + b) * 1024;
    float p = 0.f;
    for (int k = lane; k < 1024; k += 64) p += q[k] * kk[k];
    #pragma unroll
    for (int off = 32; off; off >>= 1) p += __shfl_down(p, off);
    if (lane == 0) sc[s] = p * SCALE_;
  }
  __syncthreads();
  float mx = -1e30f;
  for (int s = 0; s < si; ++s) mx = fmaxf(mx, sc[s]);
  float den = 0.f;
  for (int s = 0; s < si; ++s) den += expf(sc[s] - mx);
  float inv = 1.f / den;
  float4 accv = {0.f, 0.f, 0.f, 0.f};
  for (int s = 0; s < si; ++s) {
    float a = expf(sc[s] - mx) * inv;
    float4 vv = ((const float4*)(vbank + ((size_t)s * 16 + b) * 1024))[tid];
    accv.x += a * vv.x; accv.y += a * vv.y; accv.z += a * vv.z; accv.w += a * vv.w;
  }
  ((float4*)(R + (size_t)row * 1024))[tid] = accv;
}

// GI = [h1, R, h1-R] bf16, K=3072
__global__ __launch_bounds__(256)
void build_gi(const ushort* __restrict__ H1B, const float* __restrict__ R,
              ushort* __restrict__ GI)
{
  size_t r = blockIdx.x;
  int c4 = threadIdx.x * 4;
  ushort4 h4 = *(const ushort4*)(H1B + r * 1024 + c4);
  float4 rv = *(const float4*)(R + r * 1024 + c4);
  *(ushort4*)(GI + r * 3072 + c4) = h4;
  ushort4 rb; rb.x = f2b(rv.x); rb.y = f2b(rv.y); rb.z = f2b(rv.z); rb.w = f2b(rv.w);
  *(ushort4*)(GI + r * 3072 + 1024 + c4) = rb;
  ushort4 d;
  d.x = f2b(b2f(h4.x) - rv.x); d.y = f2b(b2f(h4.y) - rv.y);
  d.z = f2b(b2f(h4.z) - rv.z); d.w = f2b(b2f(h4.w) - rv.w);
  *(ushort4*)(GI + r * 3072 + 2048 + c4) = d;
}

// mix = gate*h1 + (1-gate)*R  -> bf16
__global__ __launch_bounds__(256)
void build_mix(const float* __restrict__ G, const ushort* __restrict__ H1B,
               const float* __restrict__ R, ushort* __restrict__ M)
{
  size_t r = blockIdx.x;
  int c4 = threadIdx.x * 4;
  float4 g = *(const float4*)(G + r * 1024 + c4);
  ushort4 h = *(const ushort4*)(H1B + r * 1024 + c4);
  float4 rv = *(const float4*)(R + r * 1024 + c4);
  ushort4 o;
  o.x = f2b(g.x * b2f(h.x) + (1.f - g.x) * rv.x);
  o.y = f2b(g.y * b2f(h.y) + (1.f - g.y) * rv.y);
  o.z = f2b(g.z * b2f(h.z) + (1.f - g.z) * rv.z);
  o.w = f2b(g.w * b2f(h.w) + (1.f - g.w) * rv.w);
  *(ushort4*)(M + r * 1024 + c4) = o;
}

// CAT = [h1, (t>=16 ? out : 0)] bf16, K=2048
__global__ __launch_bounds__(256)
void build_cat(const ushort* __restrict__ H1B, const float* __restrict__ O,
               ushort* __restrict__ C)
{
  size_t r = blockIdx.x;
  int c4 = threadIdx.x * 4;
  *(ushort4*)(C + r * 2048 + c4) = *(const ushort4*)(H1B + r * 1024 + c4);
  ushort4 o;
  if (r >= 256) {
    float4 v = *(const float4*)(O + r * 1024 + c4);
    o.x = f2b(v.x); o.y = f2b(v.y); o.z = f2b(v.z); o.w = f2b(v.w);
  } else { o.x = o.y = o.z = o.w = 0; }
  *(ushort4*)(C + r * 2048 + 1024 + c4) = o;
}

extern "C" void kernel_launch(void* const* d_in, const int* in_sizes, int n_in,
                              void* d_out, int out_size, void* d_ws, size_t ws_size,
                              hipStream_t stream) {
  const float* x     = (const float*)d_in[0];
  const float* W_ip  = (const float*)d_in[1];
  const float* b_ip  = (const float*)d_in[2];
  const float* g_ip  = (const float*)d_in[3];
  const float* be_ip = (const float*)d_in[4];
  const float* W_ih0 = (const float*)d_in[5];
  const float* W_hh0 = (const float*)d_in[6];
  const float* b_ih0 = (const float*)d_in[7];
  const float* b_hh0 = (const float*)d_in[8];
  const float* W_ih1 = (const float*)d_in[9];
  const float* W_hh1 = (const float*)d_in[10];
  const float* b_ih1 = (const float*)d_in[11];
  const float* b_hh1 = (const float*)d_in[12];
  const float* Wq    = (const float*)d_in[13];
  const float* Wk    = (const float*)d_in[14];
  const float* Wv    = (const float*)d_in[15];
  const float* Wg1   = (const float*)d_in[16];
  const float* bg1   = (const float*)d_in[17];
  const float* Wg2   = (const float*)d_in[18];
  const float* bg2   = (const float*)d_in[19];
  const float* Wo    = (const float*)d_in[20];
  const float* bo    = (const float*)d_in[21];
  const float* Wf    = (const float*)d_in[22];
  const float* bff   = (const float*)d_in[23];
  const float* g_f   = (const float*)d_in[24];
  const float* be_f  = (const float*)d_in[25];
  float* out = (float*)d_out;
  char* ws = (char*)d_ws;
  const size_t MB = (size_t)1 << 20;
  const size_t KB = (size_t)1 << 10;

  // bf16 weight pool (offsets in elements)
  ushort* WB = (ushort*)(ws);
  ushort* wipB  = WB;             // 1M
  ushort* wih0B = WB + 1*1048576; // 4M
  ushort* whh0B = WB + 5*1048576;
  ushort* wih1B = WB + 9*1048576;
  ushort* whh1B = WB + 13*1048576;
  ushort* wqB   = WB + 17*1048576;
  ushort* wkB   = WB + 18*1048576;
  ushort* wvB   = WB + 19*1048576;
  ushort* wg1B  = WB + 20*1048576; // 3M
  ushort* wg2B  = WB + 23*1048576;
  ushort* woB   = WB + 24*1048576;
  ushort* wfB   = WB + 25*1048576; // 2M -> ends 27M elems = 54MB

  ushort* XB   = (ushort*)(ws + 54 * MB);   // 8MB: x bf16, later XPB
  float*  XP   = (float*)(ws + 62 * MB);    // 16MB: input_proj pre-LN, later Q
  float*  Qf   = XP;
  char*   SCR  = ws + 78 * MB;              // 48MB scratch region
  ushort* Z0T  = (ushort*)SCR;              // 32MB bf16 [T*B,4096]
  ushort* GIB  = (ushort*)SCR;              // 24MB (after loop)
  ushort* G1B  = (ushort*)(SCR + 24 * MB);  // 8MB
  float*  GT   = (float*)(SCR + 32 * MB);   // 16MB
  ushort* MIXB = (ushort*)SCR;              // 8MB
  float*  OUTB = (float*)(SCR + 8 * MB);    // 16MB
  ushort* CATB = (ushort*)(SCR + 24 * MB);  // 16MB
  float*  FB   = (float*)SCR;               // 16MB
  ushort* H1B  = (ushort*)(ws + 126 * MB);  // 8MB
  // HP lives in the R region during phase C (R is written only afterwards)
  ushort* HP   = (ushort*)(ws + 134 * MB);  // 257*32KB = 8.22MB
  float*  R    = (float*)(ws + 134 * MB);   // 16MB (after phase C)
  char*   ST   = ws + 150 * MB;
  int*    flag0 = (int*)(ST);               // 258 ints
  int*    flag1 = (int*)(ST + 4 * KB);      // 256 ints
  const ushort* ZPc = (const ushort*)(ST + 8 * KB);   // 32KB zeros
  float*  KSUM = (float*)(ST + 64 * KB);          // 1MB
  ushort* KSB  = (ushort*)(ST + 1088 * KB);       // 0.5MB
  float*  KBf  = (float*)(ST + 1600 * KB);        // 1MB
  float*  VBf  = (float*)(ST + 2624 * KB);        // 1MB
  ushort* VINB = (ushort*)(ST + 3648 * KB);       // 0.5MB

  // zero flags + h1(-1) zero-page (40KB); HP slot0 zeroed separately
  hipMemsetAsync(ST, 0, 40 * KB, stream);
  hipMemsetAsync(HP, 0, 32 * KB, stream);

  dim3 blk(256);
  auto cvt = [&](const float* src, ushort* dst, int n) {
    cvt_bf16<<<dim3((n / 4 + 255) / 256), blk, 0, stream>>>(src, dst, n);
  };
  // weight + input conversions
  cvt(x,     XB,    4194304);
  cvt(W_ip,  wipB,  1048576);
  cvt(W_ih0, wih0B, 4194304);
  cvt(W_hh0, whh0B, 4194304);
  cvt(W_ih1, wih1B, 4194304);
  cvt(W_hh1, whh1B, 4194304);
  cvt(Wq,    wqB,   1048576);
  cvt(Wk,    wkB,   1048576);
  cvt(Wv,    wvB,   1048576);
  cvt(Wg1,   wg1B,  3145728);
  cvt(Wg2,   wg2B,  1048576);
  cvt(Wo,    woB,   1048576);
  cvt(Wf,    wfB,   2097152);

  // Phase A: XP = x@W_ip^T + b_ip ; XPB = relu(LN(XP)) (bf16, stored in XB space)
  gemm_bf16<0,0><<<dim3(1024/128, 4096/128), blk, 0, stream>>>(
      XB, wipB, b_ip, XP, nullptr, 4096, 1024, 1024, 1.f);
  ln_relu_bf16<<<4096, blk, 0, stream>>>(XP, g_ip, be_ip, XB);
  // Phase B: Z0T = XPB@W_ih0^T + b_ih0, rows remapped to t*16+b, bf16
  gemm_bf16<0,1><<<dim3(4096/128, 4096/128), blk, 0, stream>>>(
      XB, wih0B, b_ih0, nullptr, Z0T, 4096, 4096, 1024, 1.f);
  // Phase C: single persistent cooperative kernel, all 256 steps
  {
    void* kargs[] = {
      (void*)&Z0T, (void*)&whh0B, (void*)&b_hh0,
      (void*)&wih1B, (void*)&whh1B, (void*)&b_ih1, (void*)&b_hh1,
      (void*)&HP, (void*)&H1B, (void*)&ZPc, (void*)&KSUM,
      (void*)&flag0, (void*)&flag1
    };
    hipLaunchCooperativeKernel((const void*)lstm_persistent,
                               dim3(128), dim3(512), kargs, 0, stream);
  }
  // Phase D: kbank / vbank
  cvt(KSUM, KSB, 262144);
  gemm_bf16<0,0><<<dim3(1024/128, 256/128), blk, 0, stream>>>(
      KSB, wkB, nullptr, KBf, nullptr, 256, 1024, 1024, 1.f/16.f);
  vgather<<<256, blk, 0, stream>>>(H1B, VINB);
  gemm_bf16<0,0><<<dim3(1024/128, 256/128), blk, 0, stream>>>(
      VINB, wvB, nullptr, VBf, nullptr, 256, 1024, 1024, 1.f);
  // Phase E: retrieval + gate + output
  gemm_bf16<0,0><<<dim3(1024/128, 4096/128), blk, 0, stream>>>(
      H1B, wqB, nullptr, Qf, nullptr, 4096, 1024, 1024, 1.f);
  attn_kernel<<<4096, blk, 0, stream>>>(Qf, KBf, VBf, R);
  build_gi<<<4096, blk, 0, stream>>>(H1B, R, GIB);
  gemm_bf16<1,0><<<dim3(1024/128, 4096/128), blk, 0, stream>>>(
      GIB, wg1B, bg1, nullptr, G1B, 4096, 1024, 3072, 1.f);
  gemm_bf16<2,0><<<dim3(1024/128, 4096/128), blk, 0, stream>>>(
      G1B, wg2B, bg2, GT, nullptr, 4096, 1024, 1024, 1.f);
  build_mix<<<4096, blk, 0, stream>>>(GT, H1B, R, MIXB);
  gemm_bf16<0,0><<<dim3(1024/128, 4096/128), blk, 0, stream>>>(
      MIXB, woB, bo, OUTB, nullptr, 4096, 1024, 1024, 1.f);
  build_cat<<<4096, blk, 0, stream>>>(H1B, OUTB, CATB);
  gemm_bf16<0,0><<<dim3(1024/128, 4096/128), blk, 0, stream>>>(
      CATB, wfB, bff, FB, nullptr, 4096, 1024, 2048, 1.f);
  ln_relu_final<<<4096, blk, 0, stream>>>(FB, g_f, be_f, out);
}